// Round 4
// baseline (20531.972 us; speedup 1.0000x reference)
//
#include <hip/hip_runtime.h>

// ---------------------------------------------------------------------------
// HybridThoughtAwareAttention  (B=2,S=2048,E=1024,H=16,D=64,K_TOP=64,M=256)
// Round 4: np-fp32(BLAS)-mimic q/k GEMM (k-sequential fma, KC=384 panels) +
// fp64 scores + exact radix top-64 + boundary HEDGING (blend of the two
// candidate selections weighted by flip probability). Rest fp32.
// ---------------------------------------------------------------------------

constexpr int cB = 2, cS = 2048, cE = 1024, cH = 16, cD = 64, cKTOP = 64, cM = 256;
constexpr float cEPS = 1e-6f;

__device__ __forceinline__ unsigned long long d2key(double d) {
    unsigned long long u = (unsigned long long)__double_as_longlong(d);
    return (u & 0x8000000000000000ull) ? ~u : (u | 0x8000000000000000ull);
}
__device__ __forceinline__ double key2d(unsigned long long k) {
    unsigned long long u = (k & 0x8000000000000000ull) ? (k & 0x7FFFFFFFFFFFFFFFull) : ~k;
    return __longlong_as_double((long long)u);
}

// ---------------------------------------------------------------------------
// OpenBLAS-sgemm-mimicking fp32 GEMM for Qs/Ks: per-element strictly
// k-ascending single-accumulator fma chain, KC=384 panel splits (384/768),
// fp32 panel->C accumulation. 64x64 tile, BK=16, 4x4 per thread.
// ---------------------------------------------------------------------------
__global__ __launch_bounds__(256)
void gemm_qk_blas(const float* __restrict__ A,
                  const float* __restrict__ W,
                  const float* __restrict__ bias,
                  float* __restrict__ C, int K, int N)
{
    __shared__ __align__(16) float As[16][68];
    __shared__ __align__(16) float Bs[16][68];
    const int t  = threadIdx.x;
    const int r0 = blockIdx.y * 64;
    const int c0 = blockIdx.x * 64;
    const int tm = t >> 4, tn = t & 15;
    float pacc[4][4] = {};     // current panel accumulator
    float cacc[4][4] = {};     // C accumulated across panels

    const int ar = t >> 2, ak = (t & 3) * 4;
    const int bk = t >> 4, bc = (t & 15) * 4;

    for (int k0 = 0; k0 < K; k0 += 16) {
        const float4 av = *(const float4*)(A + (size_t)(r0 + ar) * K + (k0 + ak));
        const float4 bv = *(const float4*)(W + (size_t)(k0 + bk) * N + (c0 + bc));
        As[ak + 0][ar] = av.x;
        As[ak + 1][ar] = av.y;
        As[ak + 2][ar] = av.z;
        As[ak + 3][ar] = av.w;
        *(float4*)&Bs[bk][bc] = bv;
        __syncthreads();
        #pragma unroll
        for (int kk = 0; kk < 16; ++kk) {
            const float4 a4 = *(const float4*)&As[kk][tm * 4];
            const float4 b4 = *(const float4*)&Bs[kk][tn * 4];
            const float a[4]  = {a4.x, a4.y, a4.z, a4.w};
            const float bb[4] = {b4.x, b4.y, b4.z, b4.w};
            #pragma unroll
            for (int i = 0; i < 4; ++i)
                #pragma unroll
                for (int j = 0; j < 4; ++j)
                    pacc[i][j] = fmaf(a[i], bb[j], pacc[i][j]);
        }
        __syncthreads();
        const int kn = k0 + 16;
        if (kn == 384 || kn == 768 || kn == K) {   // OpenBLAS KC=384 panel flush
            #pragma unroll
            for (int i = 0; i < 4; ++i)
                #pragma unroll
                for (int j = 0; j < 4; ++j) {
                    cacc[i][j] = cacc[i][j] + pacc[i][j];
                    pacc[i][j] = 0.f;
                }
        }
    }
    #pragma unroll
    for (int i = 0; i < 4; ++i) {
        const int r = r0 + tm * 4 + i;
        const int c = c0 + tn * 4;
        float4 v;
        v.x = cacc[i][0] + bias[c + 0];
        v.y = cacc[i][1] + bias[c + 1];
        v.z = cacc[i][2] + bias[c + 2];
        v.w = cacc[i][3] + bias[c + 3];
        *(float4*)&C[(size_t)r * N + c] = v;
    }
}

// ---------------------------------------------------------------------------
// fp32 GEMM (fast, smooth path): C = A @ W (+bias). 128x128 tile, BK=8.
// ---------------------------------------------------------------------------
__global__ __launch_bounds__(256)
void gemm_f32(const float* __restrict__ A,
              const float* __restrict__ W,
              const float* __restrict__ bias,
              float* __restrict__ C, int K, int N)
{
    __shared__ __align__(16) float As[8][132];
    __shared__ __align__(16) float Bs[8][132];
    const int t  = threadIdx.x;
    const int r0 = blockIdx.y * 128;
    const int c0 = blockIdx.x * 128;
    const int tm = t >> 4, tn = t & 15;
    float acc[8][8] = {};

    const int ar = t >> 1;
    const int ak = (t & 1) * 4;
    const int bk = t >> 5;
    const int bc = (t & 31) * 4;

    for (int k0 = 0; k0 < K; k0 += 8) {
        const float4 av = *(const float4*)(A + (size_t)(r0 + ar) * K + (k0 + ak));
        const float4 bv = *(const float4*)(W + (size_t)(k0 + bk) * N + (c0 + bc));
        As[ak + 0][ar] = av.x;
        As[ak + 1][ar] = av.y;
        As[ak + 2][ar] = av.z;
        As[ak + 3][ar] = av.w;
        *(float4*)&Bs[bk][bc] = bv;
        __syncthreads();
        #pragma unroll
        for (int kk = 0; kk < 8; ++kk) {
            const float4 a0 = *(const float4*)&As[kk][tm * 4];
            const float4 a1 = *(const float4*)&As[kk][tm * 4 + 64];
            const float4 b0 = *(const float4*)&Bs[kk][tn * 4];
            const float4 b1 = *(const float4*)&Bs[kk][tn * 4 + 64];
            const float a[8]  = {a0.x, a0.y, a0.z, a0.w, a1.x, a1.y, a1.z, a1.w};
            const float bb[8] = {b0.x, b0.y, b0.z, b0.w, b1.x, b1.y, b1.z, b1.w};
            #pragma unroll
            for (int i = 0; i < 8; ++i)
                #pragma unroll
                for (int j = 0; j < 8; ++j)
                    acc[i][j] = fmaf(a[i], bb[j], acc[i][j]);
        }
        __syncthreads();
    }
    #pragma unroll
    for (int ih = 0; ih < 2; ++ih) {
        #pragma unroll
        for (int ii = 0; ii < 4; ++ii) {
            const int r = r0 + ih * 64 + tm * 4 + ii;
            const int i = ih * 4 + ii;
            #pragma unroll
            for (int jh = 0; jh < 2; ++jh) {
                const int c = c0 + jh * 64 + tn * 4;
                float4 v;
                v.x = acc[i][jh * 4 + 0];
                v.y = acc[i][jh * 4 + 1];
                v.z = acc[i][jh * 4 + 2];
                v.w = acc[i][jh * 4 + 3];
                if (bias) {
                    v.x += bias[c + 0]; v.y += bias[c + 1];
                    v.z += bias[c + 2]; v.w += bias[c + 3];
                }
                *(float4*)&C[(size_t)r * N + c] = v;
            }
        }
    }
}

// ---------------------------------------------------------------------------
// K transpose: (B,S,H,D) fp32 -> (B,H,D,S)
// ---------------------------------------------------------------------------
__global__ __launch_bounds__(256)
void transpose_k(const float* __restrict__ Ks, float* __restrict__ KsT)
{
    __shared__ float tile[64][65];
    const int t  = threadIdx.x;
    const int bh = blockIdx.y;
    const int b  = bh >> 4;
    const int h64 = (bh & 15) * 64;
    const int s0 = blockIdx.x * 64;
    const int sr = t >> 4;
    const int d4 = (t & 15) * 4;
    #pragma unroll
    for (int i = 0; i < 4; ++i) {
        const int s = sr + 16 * i;
        float4 v = *(const float4*)&Ks[((size_t)(b * cS + s0 + s)) * cE + h64 + d4];
        tile[s][d4 + 0] = v.x; tile[s][d4 + 1] = v.y;
        tile[s][d4 + 2] = v.z; tile[s][d4 + 3] = v.w;
    }
    __syncthreads();
    const int s4 = (t & 15) * 4;
    #pragma unroll
    for (int i = 0; i < 4; ++i) {
        const int d = (t >> 4) + 16 * i;
        float4 w;
        w.x = tile[s4 + 0][d]; w.y = tile[s4 + 1][d];
        w.z = tile[s4 + 2][d]; w.w = tile[s4 + 3][d];
        *(float4*)&KsT[((size_t)(bh * 64 + d)) * cS + s0 + s4] = w;
    }
}

// ---------------------------------------------------------------------------
// Sparse attention with boundary hedging. 4 q-rows/block (1 wave per row).
// fp64 scores from fp32 q,k; exact 64-bit radix top-64; blend of the two
// candidate selections (swap 64th<->65th) weighted by flip probability.
// LDS ~126 KB.
// ---------------------------------------------------------------------------
__global__ __launch_bounds__(256)
void sparse_attn(const float* __restrict__ Q, const float* __restrict__ KT,
                 const float* __restrict__ V, float* __restrict__ O)
{
    __shared__ __align__(16) double scod[4][2048];   // 64 KB; aliased by Vt in phase D
    __shared__ __align__(16) float  Kt[64][68];      // 17.4 KB
    __shared__ __align__(16) double Qd[4][64];       // 2 KB
    __shared__ unsigned int hist[4][256];            // 4 KB
    __shared__ __align__(16) float  pArr[4][2048];   // 32 KB (coef * exp)
    __shared__ __align__(16) float  red[4][4][64];   // 4 KB
    __shared__ unsigned long long selpref[4];
    __shared__ int selneed[4];

    const int t    = threadIdx.x;
    const int bh   = blockIdx.y;
    const int b    = bh >> 4;
    const int h64  = (bh & 15) * 64;
    const int q0   = blockIdx.x * 4;
    const int tq   = t >> 6;        // wave id == q-row
    const int lane = t & 63;

    Qd[tq][lane] = (double)Q[((size_t)(b * cS + q0 + tq)) * cE + h64 + lane];
    if (t < 4) { selpref[t] = 0ull; selneed[t] = cKTOP; }

    const float* Khead = KT + (size_t)bh * 64 * cS;

    // ---- phase A: fp64 scores from fp32 q,k ----
    double mloc = -1.0e308;
    for (int kt = 0; kt < 32; ++kt) {
        const int k0 = kt * 64;
        __syncthreads();
        #pragma unroll
        for (int i = 0; i < 16; ++i) {
            const int idx = t + 256 * i;
            const int d = idx >> 6, c = idx & 63;
            Kt[d][c] = Khead[(size_t)d * cS + k0 + c];
        }
        __syncthreads();
        double acc = 0.0;
        #pragma unroll 16
        for (int d = 0; d < 64; ++d)
            acc = fma(Qd[tq][d], (double)Kt[d][lane], acc);
        acc *= 0.125;
        scod[tq][k0 + lane] = acc;
        mloc = fmax(mloc, acc);
    }
    #pragma unroll
    for (int off = 32; off >= 1; off >>= 1)
        mloc = fmax(mloc, __shfl_xor(mloc, off));
    const double m = mloc;                        // row max (all lanes)

    // ---- phase B: exact 64-bit radix select of 64th-largest ----
    for (int r = 0; r < 8; ++r) {
        const int shift = 56 - 8 * r;
        __syncthreads();
        for (int i = t; i < 1024; i += 256) ((unsigned int*)hist)[i] = 0u;
        __syncthreads();
        const unsigned long long pr  = selpref[tq];
        const unsigned long long mhi = (r == 0) ? 0ull : ((~0ull) << (shift + 8));
        for (int i = 0; i < 32; ++i) {
            const unsigned long long k = d2key(scod[tq][lane + 64 * i]);
            if ((k & mhi) == pr)
                atomicAdd(&hist[tq][(unsigned int)((k >> shift) & 255ull)], 1u);
        }
        __syncthreads();
        if (lane == 0) {
            int need = selneed[tq];
            const unsigned long long base = selpref[tq];
            for (int bin = 255; bin >= 0; --bin) {
                const int c = (int)hist[tq][bin];
                if (c >= need) {
                    selpref[tq] = base | ((unsigned long long)bin << shift);
                    selneed[tq] = need;
                    break;
                }
                need -= c;
            }
        }
    }
    __syncthreads();
    const double T64 = key2d(selpref[tq]);

    // ---- phase B2: s65 = max score strictly below T64; hedge weight ----
    double m2 = -1.0e308;
    for (int i = 0; i < 32; ++i) {
        const double s = scod[tq][lane + 64 * i];
        if (s < T64) m2 = fmax(m2, s);
    }
    #pragma unroll
    for (int off = 32; off >= 1; off >>= 1)
        m2 = fmax(m2, __shfl_xor(m2, off));
    const double s65 = m2;

    const float g  = (float)(T64 - s65);
    const float gm = fmaxf(g - 5e-7f, 0.f);
    const float wB = 0.5f * erfcf(gm * (1.0f / 2.2e-6f));   // flip probability hedge
    const float wA = 1.f - wB;

    // ---- phase C: normalizations and per-key coefficients ----
    float zs = 0.f;
    for (int i = 0; i < 32; ++i) {
        const double s = scod[tq][lane + 64 * i];
        if (s >= T64) zs += expf((float)(s - m));
    }
    #pragma unroll
    for (int off = 32; off >= 1; off >>= 1)
        zs += __shfl_xor(zs, off);
    const float ZA  = zs;
    const float e64 = expf((float)(T64 - m));
    const float e65 = expf((float)(s65 - m));
    const float ZB  = ZA - e64 + e65;
    const float cIn = wA / ZA + wB / ZB;   // keys strictly above threshold
    const float c64 = wA / ZA;             // the 64th key (set A only)
    const float c65 = wB / ZB;             // the 65th key (set B only)

    for (int i = 0; i < 32; ++i) {
        const int col = lane + 64 * i;
        const double s = scod[tq][col];
        float c = 0.f;
        if (s > T64)       c = cIn;
        else if (s == T64) c = c64;
        else if (s == s65) c = c65;
        pArr[tq][col] = (c != 0.f) ? c * expf((float)(s - m)) : 0.f;
    }

    // ---- phase D: weighted attn @ V (k split over 4 waves) ----
    float* VtF = reinterpret_cast<float*>(&scod[0][0]);   // Vt[64][68] over dead scod
    const int kg = tq;
    const int rr = (lane >> 4) & 3;
    const int d4 = (lane & 15) * 4;
    float4 o = {0.f, 0.f, 0.f, 0.f};
    for (int vt = 0; vt < 32; ++vt) {
        const int k0 = vt * 64;
        __syncthreads();
        #pragma unroll
        for (int i = 0; i < 4; ++i) {
            const int r = (t >> 4) + 16 * i;
            const int c4 = (t & 15) * 4;
            *(float4*)&VtF[r * 68 + c4] =
                *(const float4*)&V[((size_t)(b * cS + k0 + r)) * cE + h64 + c4];
        }
        __syncthreads();
        #pragma unroll
        for (int k8 = 0; k8 < 16; ++k8) {
            const int kk = kg * 16 + k8;
            const float p = pArr[rr][k0 + kk];
            const float4 vv = *(const float4*)&VtF[kk * 68 + d4];
            o.x = fmaf(p, vv.x, o.x); o.y = fmaf(p, vv.y, o.y);
            o.z = fmaf(p, vv.z, o.z); o.w = fmaf(p, vv.w, o.w);
        }
    }
    __syncthreads();
    *(float4*)&red[kg][rr][d4] = o;
    __syncthreads();
    {
        const int row = t >> 6, d = t & 63;
        const float v = red[0][row][d] + red[1][row][d]
                      + red[2][row][d] + red[3][row][d];
        O[((size_t)(b * cS + q0 + row)) * cE + h64 + d] = v;
    }
}

// ---------------------------------------------------------------------------
// Performer: kv[m,d] = sum_s phi_k[s,m] * v[s,d];  z[m] = sum_s phi_k[s,m]
// ---------------------------------------------------------------------------
__global__ __launch_bounds__(256)
void perf_kv(const float* __restrict__ Kp, const float* __restrict__ Vp,
             const float* __restrict__ Wfeat,
             float* __restrict__ kv, float* __restrict__ z)
{
    __shared__ __align__(16) float Wf[64][68];
    __shared__ __align__(16) float Kt[64][68];
    __shared__ __align__(16) float Vt[64][68];
    __shared__ __align__(16) float Ph[64][68];
    const int t   = threadIdx.x;
    const int mc  = blockIdx.x;
    const int bh  = blockIdx.y;
    const int b   = bh >> 4;
    const int h64 = (bh & 15) * 64;
    const int m0  = mc * 64;

    for (int i = t; i < 64 * 64; i += 256) {
        const int d = i >> 6, mm = i & 63;
        Wf[d][mm] = Wfeat[d * cM + m0 + mm];
    }

    const int lr = t >> 4, lc = (t & 15) * 4;
    const int mph = t & 63, sph = t >> 6;
    const int d = t & 63, mrow = t >> 6;
    float akv[16];
    #pragma unroll
    for (int j = 0; j < 16; ++j) akv[j] = 0.f;
    float az = 0.f;

    for (int st = 0; st < 32; ++st) {
        const int s0 = st * 64;
        __syncthreads();
        #pragma unroll
        for (int i = 0; i < 4; ++i) {
            const int row = lr + 16 * i;
            const size_t base = ((size_t)(b * cS + s0 + row)) * cE + h64 + lc;
            *(float4*)&Kt[row][lc] = *(const float4*)&Kp[base];
            *(float4*)&Vt[row][lc] = *(const float4*)&Vp[base];
        }
        __syncthreads();
        #pragma unroll
        for (int j = 0; j < 16; ++j) {
            const int s = sph + 4 * j;
            float acc = 0.f;
            for (int dd = 0; dd < 64; ++dd)
                acc = fmaf(Kt[s][dd], Wf[dd][mph], acc);
            Ph[s][mph] = fmaxf(acc, 0.f) + cEPS;
        }
        __syncthreads();
        #pragma unroll
        for (int j = 0; j < 16; ++j) {
            const int mm = mrow + 4 * j;
            float a = akv[j];
            for (int ss = 0; ss < 64; ++ss)
                a = fmaf(Ph[ss][mm], Vt[ss][d], a);
            akv[j] = a;
        }
        if (t < 64) {
            float a = az;
            for (int ss = 0; ss < 64; ++ss) a += Ph[ss][t];
            az = a;
        }
    }
    #pragma unroll
    for (int j = 0; j < 16; ++j)
        kv[((size_t)bh * cM + m0 + mrow + 4 * j) * cD + d] = akv[j];
    if (t < 64) z[(size_t)bh * cM + m0 + t] = az;
}

// ---------------------------------------------------------------------------
// Performer: num = phi_q @ kv; den = phi_q . z + EPS; Ap = num/den.
// ---------------------------------------------------------------------------
__global__ __launch_bounds__(256)
void perf_numden(const float* __restrict__ Qp, const float* __restrict__ Wfeat,
                 const float* __restrict__ kv, const float* __restrict__ z,
                 float* __restrict__ Ap)
{
    __shared__ __align__(16) float Wf[64][68];
    __shared__ __align__(16) float Qt[64][68];
    __shared__ __align__(16) float KV[64][68];
    __shared__ __align__(16) float Ph[64][68];
    __shared__ float zl[64];
    __shared__ float denl[64];
    const int t   = threadIdx.x;
    const int stb = blockIdx.x;
    const int bh  = blockIdx.y;
    const int b   = bh >> 4;
    const int h64 = (bh & 15) * 64;
    const int s0  = stb * 64;
    const int lr = t >> 4, lc = (t & 15) * 4;
    #pragma unroll
    for (int i = 0; i < 4; ++i) {
        const int row = lr + 16 * i;
        *(float4*)&Qt[row][lc] =
            *(const float4*)&Qp[((size_t)(b * cS + s0 + row)) * cE + h64 + lc];
    }
    const int mph = t & 63, sph = t >> 6;
    const int d = t & 63, srow = t >> 6;
    float num[16];
    #pragma unroll
    for (int j = 0; j < 16; ++j) num[j] = 0.f;
    float denreg = 0.f;

    for (int mcI = 0; mcI < 4; ++mcI) {
        const int m0 = mcI * 64;
        __syncthreads();
        for (int i = t; i < 64 * 64; i += 256) {
            const int dd = i >> 6, mm = i & 63;
            Wf[dd][mm] = Wfeat[dd * cM + m0 + mm];
        }
        #pragma unroll
        for (int i = 0; i < 4; ++i) {
            const int row = lr + 16 * i;
            *(float4*)&KV[row][lc] =
                *(const float4*)&kv[((size_t)bh * cM + m0 + row) * cD + lc];
        }
        if (t < 64) zl[t] = z[(size_t)bh * cM + m0 + t];
        __syncthreads();
        #pragma unroll
        for (int j = 0; j < 16; ++j) {
            const int s = sph + 4 * j;
            float acc = 0.f;
            for (int dd = 0; dd < 64; ++dd)
                acc = fmaf(Qt[s][dd], Wf[dd][mph], acc);
            Ph[s][mph] = fmaxf(acc, 0.f) + cEPS;
        }
        __syncthreads();
        #pragma unroll
        for (int j = 0; j < 16; ++j) {
            const int s = srow + 4 * j;
            float a = num[j];
            for (int mm = 0; mm < 64; ++mm)
                a = fmaf(Ph[s][mm], KV[mm][d], a);
            num[j] = a;
        }
        if (t < 64) {
            float a = denreg;
            for (int mm = 0; mm < 64; ++mm) a = fmaf(Ph[t][mm], zl[mm], a);
            denreg = a;
        }
    }
    __syncthreads();
    if (t < 64) denl[t] = denreg + cEPS;
    __syncthreads();
    #pragma unroll
    for (int j = 0; j < 16; ++j) {
        const int s = srow + 4 * j;
        Ap[((size_t)(b * cS + s0 + s)) * cE + h64 + d] = num[j] / denl[s];
    }
}

// ---------------------------------------------------------------------------
// Gate
// ---------------------------------------------------------------------------
__global__ __launch_bounds__(256)
void gate_avg(const float* __restrict__ x, float* __restrict__ avg)
{
    const int i = blockIdx.x * 256 + threadIdx.x;
    const int b = i >> 10, e = i & 1023;
    double acc = 0.0;
    for (int s = 0; s < cS; ++s)
        acc += (double)x[((size_t)(b * cS + s)) * cE + e];
    avg[i] = (float)(acc / (double)cS);
}

__global__ void gate_final(const float* __restrict__ avg, const float* __restrict__ Wg,
                           const float* __restrict__ bg, float* __restrict__ gates)
{
    const int t = threadIdx.x;
    const int b = t >> 6, lane = t & 63;
    float l0 = 0.f, l1 = 0.f;
    for (int e = lane; e < cE; e += 64) {
        const float a = avg[b * cE + e];
        l0 = fmaf(a, Wg[e * 2 + 0], l0);
        l1 = fmaf(a, Wg[e * 2 + 1], l1);
    }
    for (int off = 32; off >= 1; off >>= 1) {
        l0 += __shfl_down(l0, off);
        l1 += __shfl_down(l1, off);
    }
    if (lane == 0) {
        l0 += bg[0]; l1 += bg[1];
        const float m = fmaxf(l0, l1);
        const float e0 = expf(l0 - m), e1 = expf(l1 - m);
        const float s = e0 + e1;
        gates[b * 2 + 0] = e0 / s;
        gates[b * 2 + 1] = e1 / s;
    }
}

// ---------------------------------------------------------------------------
// Fused epilogue: out = gs*(As@Wos + bos) + gp*(Ap@Wop + bop)
// ---------------------------------------------------------------------------
__global__ __launch_bounds__(256)
void out_gemm(const float* __restrict__ As_, const float* __restrict__ Ap_,
              const float* __restrict__ Wos, const float* __restrict__ Wop,
              const float* __restrict__ bos, const float* __restrict__ bop,
              const float* __restrict__ gates, float* __restrict__ out)
{
    __shared__ __align__(16) float A1[16][68];
    __shared__ __align__(16) float A2[16][68];
    __shared__ __align__(16) float B1[16][68];
    __shared__ __align__(16) float B2[16][68];
    const int t  = threadIdx.x;
    const int r0 = blockIdx.y * 64, c0 = blockIdx.x * 64;
    const int tm = t >> 4, tn = t & 15;
    const int b  = r0 >> 11;
    const float gs = gates[b * 2 + 0], gp = gates[b * 2 + 1];
    float acc[4][4] = {};
    const int ar = t >> 2, ak = (t & 3) * 4;
    const int bk = t >> 4, bc = (t & 15) * 4;
    for (int k0 = 0; k0 < cE; k0 += 16) {
        const float4 a1 = *(const float4*)&As_[((size_t)(r0 + ar)) * cE + k0 + ak];
        const float4 a2 = *(const float4*)&Ap_[((size_t)(r0 + ar)) * cE + k0 + ak];
        const float4 w1 = *(const float4*)&Wos[(size_t)(k0 + bk) * cE + c0 + bc];
        const float4 w2 = *(const float4*)&Wop[(size_t)(k0 + bk) * cE + c0 + bc];
        A1[ak + 0][ar] = a1.x * gs; A1[ak + 1][ar] = a1.y * gs;
        A1[ak + 2][ar] = a1.z * gs; A1[ak + 3][ar] = a1.w * gs;
        A2[ak + 0][ar] = a2.x * gp; A2[ak + 1][ar] = a2.y * gp;
        A2[ak + 2][ar] = a2.z * gp; A2[ak + 3][ar] = a2.w * gp;
        *(float4*)&B1[bk][bc] = w1;
        *(float4*)&B2[bk][bc] = w2;
        __syncthreads();
        #pragma unroll
        for (int kk = 0; kk < 16; ++kk) {
            const float4 a1v = *(const float4*)&A1[kk][tm * 4];
            const float4 b1v = *(const float4*)&B1[kk][tn * 4];
            const float4 a2v = *(const float4*)&A2[kk][tm * 4];
            const float4 b2v = *(const float4*)&B2[kk][tn * 4];
            const float av1[4] = {a1v.x, a1v.y, a1v.z, a1v.w};
            const float bw1[4] = {b1v.x, b1v.y, b1v.z, b1v.w};
            const float av2[4] = {a2v.x, a2v.y, a2v.z, a2v.w};
            const float bw2[4] = {b2v.x, b2v.y, b2v.z, b2v.w};
            #pragma unroll
            for (int i = 0; i < 4; ++i)
                #pragma unroll
                for (int j = 0; j < 4; ++j)
                    acc[i][j] = fmaf(av2[i], bw2[j], fmaf(av1[i], bw1[j], acc[i][j]));
        }
        __syncthreads();
    }
    #pragma unroll
    for (int i = 0; i < 4; ++i) {
        const int r = r0 + tm * 4 + i;
        const int c = c0 + tn * 4;
        float4 v;
        v.x = acc[i][0] + gs * bos[c + 0] + gp * bop[c + 0];
        v.y = acc[i][1] + gs * bos[c + 1] + gp * bop[c + 1];
        v.z = acc[i][2] + gs * bos[c + 2] + gp * bop[c + 2];
        v.w = acc[i][3] + gs * bos[c + 3] + gp * bop[c + 3];
        *(float4*)&out[(size_t)r * cE + c] = v;
    }
}

// ---------------------------------------------------------------------------
extern "C" void kernel_launch(void* const* d_in, const int* in_sizes, int n_in,
                              void* d_out, int out_size, void* d_ws, size_t ws_size,
                              hipStream_t stream)
{
    (void)in_sizes; (void)n_in; (void)out_size; (void)ws_size;
    const float* x     = (const float*)d_in[0];
    const float* Wq_s  = (const float*)d_in[1];
    const float* Wk_s  = (const float*)d_in[2];
    const float* Wv_s  = (const float*)d_in[3];
    const float* Wo_s  = (const float*)d_in[4];
    const float* bq_s  = (const float*)d_in[5];
    const float* bk_s  = (const float*)d_in[6];
    const float* bv_s  = (const float*)d_in[7];
    const float* bo_s  = (const float*)d_in[8];
    const float* Wq_p  = (const float*)d_in[9];
    const float* Wk_p  = (const float*)d_in[10];
    const float* Wv_p  = (const float*)d_in[11];
    const float* Wo_p  = (const float*)d_in[12];
    const float* bo_p  = (const float*)d_in[13];
    const float* Wfeat = (const float*)d_in[14];
    const float* Wg    = (const float*)d_in[15];
    const float* bg    = (const float*)d_in[16];

    float* ws = (float*)d_ws;
    const size_t NRE = (size_t)cB * cS * cE;
    float* Qs    = ws;              // later: Qp
    float* Ks    = Qs + NRE;        // later: Kp
    float* KsT   = Ks + NRE;        // later: Apout
    float* Vs    = KsT + NRE;       // later: Vp
    float* Asout = Vs + NRE;
    float* kvbuf = Asout + NRE;
    float* zbuf  = kvbuf + (size_t)cB * cH * cM * cD;
    float* avg   = zbuf + (size_t)cB * cH * cM;
    float* gates = avg + (size_t)cB * cE;

    // ---- sparse branch: BLAS-mimic fp32 q/k, fp64 scores, hedged top-k ----
    gemm_qk_blas<<<dim3(16, 64), 256, 0, stream>>>(x, Wq_s, bq_s, Qs, cE, cE);
    gemm_qk_blas<<<dim3(16, 64), 256, 0, stream>>>(x, Wk_s, bk_s, Ks, cE, cE);
    gemm_f32<<<dim3(8, 32), 256, 0, stream>>>(x, Wv_s, bv_s, Vs, cE, cE);
    transpose_k<<<dim3(32, 32), 256, 0, stream>>>(Ks, KsT);
    sparse_attn<<<dim3(512, 32), 256, 0, stream>>>(Qs, KsT, Vs, Asout);

    // ---- performer branch (reuses buffers) ----
    float* Qp    = Qs;
    float* Kp    = Ks;
    float* Vp    = Vs;
    float* Apout = KsT;
    gemm_f32<<<dim3(8, 32), 256, 0, stream>>>(x, Wq_p, nullptr, Qp, cE, cE);
    gemm_f32<<<dim3(8, 32), 256, 0, stream>>>(x, Wk_p, nullptr, Kp, cE, cE);
    gemm_f32<<<dim3(8, 32), 256, 0, stream>>>(x, Wv_p, nullptr, Vp, cE, cE);
    perf_kv<<<dim3(4, 32), 256, 0, stream>>>(Kp, Vp, Wfeat, kvbuf, zbuf);
    perf_numden<<<dim3(32, 32), 256, 0, stream>>>(Qp, Wfeat, kvbuf, zbuf, Apout);

    // ---- gate + fused output ----
    gate_avg<<<dim3(8), 256, 0, stream>>>(x, avg);
    gate_final<<<dim3(1), 128, 0, stream>>>(avg, Wg, bg, gates);
    out_gemm<<<dim3(16, 64), 256, 0, stream>>>(Asout, Apout, Wo_s, Wo_p,
                                               bo_s, bo_p, gates, (float*)d_out);
}

// Round 5
// 8778.414 us; speedup vs baseline: 2.3389x; 2.3389x over previous
//
#include <hip/hip_runtime.h>

// ---------------------------------------------------------------------------
// HybridThoughtAwareAttention  (B=2,S=2048,E=1024,H=16,D=64,K_TOP=64,M=256)
// Round 5: fast sparse path. fp32 scores -> u16 quantized radix select
// (captures exact fp64 top-65 provably) -> fp64 recompute of ~66 candidates
// -> exact rank + round-4 hedge -> sparse gather PV. Semantics preserved.
// ---------------------------------------------------------------------------

constexpr int cB = 2, cS = 2048, cE = 1024, cH = 16, cD = 64, cKTOP = 64, cM = 256;
constexpr float cEPS = 1e-6f;

__device__ __forceinline__ unsigned int f2key(float f) {    // monotone f32->u32
    unsigned int u = __float_as_uint(f);
    return (u & 0x80000000u) ? ~u : (u | 0x80000000u);
}

// ---------------------------------------------------------------------------
// OpenBLAS-sgemm-mimicking fp32 GEMM for Qs/Ks (unchanged from round 4).
// ---------------------------------------------------------------------------
__global__ __launch_bounds__(256)
void gemm_qk_blas(const float* __restrict__ A,
                  const float* __restrict__ W,
                  const float* __restrict__ bias,
                  float* __restrict__ C, int K, int N)
{
    __shared__ __align__(16) float As[16][68];
    __shared__ __align__(16) float Bs[16][68];
    const int t  = threadIdx.x;
    const int r0 = blockIdx.y * 64;
    const int c0 = blockIdx.x * 64;
    const int tm = t >> 4, tn = t & 15;
    float pacc[4][4] = {};
    float cacc[4][4] = {};

    const int ar = t >> 2, ak = (t & 3) * 4;
    const int bk = t >> 4, bc = (t & 15) * 4;

    for (int k0 = 0; k0 < K; k0 += 16) {
        const float4 av = *(const float4*)(A + (size_t)(r0 + ar) * K + (k0 + ak));
        const float4 bv = *(const float4*)(W + (size_t)(k0 + bk) * N + (c0 + bc));
        As[ak + 0][ar] = av.x;
        As[ak + 1][ar] = av.y;
        As[ak + 2][ar] = av.z;
        As[ak + 3][ar] = av.w;
        *(float4*)&Bs[bk][bc] = bv;
        __syncthreads();
        #pragma unroll
        for (int kk = 0; kk < 16; ++kk) {
            const float4 a4 = *(const float4*)&As[kk][tm * 4];
            const float4 b4 = *(const float4*)&Bs[kk][tn * 4];
            const float a[4]  = {a4.x, a4.y, a4.z, a4.w};
            const float bb[4] = {b4.x, b4.y, b4.z, b4.w};
            #pragma unroll
            for (int i = 0; i < 4; ++i)
                #pragma unroll
                for (int j = 0; j < 4; ++j)
                    pacc[i][j] = fmaf(a[i], bb[j], pacc[i][j]);
        }
        __syncthreads();
        const int kn = k0 + 16;
        if (kn == 384 || kn == 768 || kn == K) {   // OpenBLAS KC=384 panel flush
            #pragma unroll
            for (int i = 0; i < 4; ++i)
                #pragma unroll
                for (int j = 0; j < 4; ++j) {
                    cacc[i][j] = cacc[i][j] + pacc[i][j];
                    pacc[i][j] = 0.f;
                }
        }
    }
    #pragma unroll
    for (int i = 0; i < 4; ++i) {
        const int r = r0 + tm * 4 + i;
        const int c = c0 + tn * 4;
        float4 v;
        v.x = cacc[i][0] + bias[c + 0];
        v.y = cacc[i][1] + bias[c + 1];
        v.z = cacc[i][2] + bias[c + 2];
        v.w = cacc[i][3] + bias[c + 3];
        *(float4*)&C[(size_t)r * N + c] = v;
    }
}

// ---------------------------------------------------------------------------
// fp32 GEMM (smooth path): 128x128 tile, BK=8. (unchanged)
// ---------------------------------------------------------------------------
__global__ __launch_bounds__(256)
void gemm_f32(const float* __restrict__ A,
              const float* __restrict__ W,
              const float* __restrict__ bias,
              float* __restrict__ C, int K, int N)
{
    __shared__ __align__(16) float As[8][132];
    __shared__ __align__(16) float Bs[8][132];
    const int t  = threadIdx.x;
    const int r0 = blockIdx.y * 128;
    const int c0 = blockIdx.x * 128;
    const int tm = t >> 4, tn = t & 15;
    float acc[8][8] = {};

    const int ar = t >> 1;
    const int ak = (t & 1) * 4;
    const int bk = t >> 5;
    const int bc = (t & 31) * 4;

    for (int k0 = 0; k0 < K; k0 += 8) {
        const float4 av = *(const float4*)(A + (size_t)(r0 + ar) * K + (k0 + ak));
        const float4 bv = *(const float4*)(W + (size_t)(k0 + bk) * N + (c0 + bc));
        As[ak + 0][ar] = av.x;
        As[ak + 1][ar] = av.y;
        As[ak + 2][ar] = av.z;
        As[ak + 3][ar] = av.w;
        *(float4*)&Bs[bk][bc] = bv;
        __syncthreads();
        #pragma unroll
        for (int kk = 0; kk < 8; ++kk) {
            const float4 a0 = *(const float4*)&As[kk][tm * 4];
            const float4 a1 = *(const float4*)&As[kk][tm * 4 + 64];
            const float4 b0 = *(const float4*)&Bs[kk][tn * 4];
            const float4 b1 = *(const float4*)&Bs[kk][tn * 4 + 64];
            const float a[8]  = {a0.x, a0.y, a0.z, a0.w, a1.x, a1.y, a1.z, a1.w};
            const float bb[8] = {b0.x, b0.y, b0.z, b0.w, b1.x, b1.y, b1.z, b1.w};
            #pragma unroll
            for (int i = 0; i < 8; ++i)
                #pragma unroll
                for (int j = 0; j < 8; ++j)
                    acc[i][j] = fmaf(a[i], bb[j], acc[i][j]);
        }
        __syncthreads();
    }
    #pragma unroll
    for (int ih = 0; ih < 2; ++ih) {
        #pragma unroll
        for (int ii = 0; ii < 4; ++ii) {
            const int r = r0 + ih * 64 + tm * 4 + ii;
            const int i = ih * 4 + ii;
            #pragma unroll
            for (int jh = 0; jh < 2; ++jh) {
                const int c = c0 + jh * 64 + tn * 4;
                float4 v;
                v.x = acc[i][jh * 4 + 0];
                v.y = acc[i][jh * 4 + 1];
                v.z = acc[i][jh * 4 + 2];
                v.w = acc[i][jh * 4 + 3];
                if (bias) {
                    v.x += bias[c + 0]; v.y += bias[c + 1];
                    v.z += bias[c + 2]; v.w += bias[c + 3];
                }
                *(float4*)&C[(size_t)r * N + c] = v;
            }
        }
    }
}

// ---------------------------------------------------------------------------
// K transpose: (B,S,H,D) fp32 -> (B,H,D,S)  (unchanged)
// ---------------------------------------------------------------------------
__global__ __launch_bounds__(256)
void transpose_k(const float* __restrict__ Ks, float* __restrict__ KsT)
{
    __shared__ float tile[64][65];
    const int t  = threadIdx.x;
    const int bh = blockIdx.y;
    const int b  = bh >> 4;
    const int h64 = (bh & 15) * 64;
    const int s0 = blockIdx.x * 64;
    const int sr = t >> 4;
    const int d4 = (t & 15) * 4;
    #pragma unroll
    for (int i = 0; i < 4; ++i) {
        const int s = sr + 16 * i;
        float4 v = *(const float4*)&Ks[((size_t)(b * cS + s0 + s)) * cE + h64 + d4];
        tile[s][d4 + 0] = v.x; tile[s][d4 + 1] = v.y;
        tile[s][d4 + 2] = v.z; tile[s][d4 + 3] = v.w;
    }
    __syncthreads();
    const int s4 = (t & 15) * 4;
    #pragma unroll
    for (int i = 0; i < 4; ++i) {
        const int d = (t >> 4) + 16 * i;
        float4 w;
        w.x = tile[s4 + 0][d]; w.y = tile[s4 + 1][d];
        w.z = tile[s4 + 2][d]; w.w = tile[s4 + 3][d];
        *(float4*)&KsT[((size_t)(bh * 64 + d)) * cS + s0 + s4] = w;
    }
}

// ---------------------------------------------------------------------------
// Sparse attention, fast path. Block = 8 q-rows, 256 threads, ~56 KB LDS
// (2 blocks/CU). fp32 scores (register tile, K from L2) -> u16 select ->
// fp64 candidate recompute -> round-4 hedge -> sparse PV gather.
// ---------------------------------------------------------------------------
__global__ __launch_bounds__(256, 2)
void sparse_attn(const float* __restrict__ Q, const float* __restrict__ KT,
                 const float* __restrict__ Ks, const float* __restrict__ V,
                 float* __restrict__ O)
{
    __shared__ unsigned short s16[8][2048];      // 32 KB quantized scores
    __shared__ float Qf[8][64];                  // 2 KB
    __shared__ unsigned int hist[8][256];        // 8 KB
    __shared__ unsigned short cidx[8][128];      // 2 KB
    __shared__ double cval[8][128];              // 8 KB
    __shared__ float cw[8][128];                 // 4 KB
    __shared__ int cnt[8];
    __shared__ int rem[8];
    __shared__ int t16[8];
    __shared__ int ncs[8];
    __shared__ double T64s[8], s65s[8], rowm[8];

    const int t   = threadIdx.x;
    const int bh  = blockIdx.y;
    const int b   = bh >> 4;
    const int h64 = (bh & 15) * 64;
    const int q0  = blockIdx.x * 8;

    if (t < 128) {
        const int r = t >> 4, c4 = (t & 15) * 4;
        *(float4*)&Qf[r][c4] =
            *(const float4*)&Q[((size_t)(b * cS + q0 + r)) * cE + h64 + c4];
    }
    if (t < 8) cnt[t] = 0;
    __syncthreads();

    // ---- phase A: fp32 scores, 8 keys x 8 rows per thread ----
    const float* KTh = KT + (size_t)bh * 64 * cS;
    float acc[8][8];
    #pragma unroll
    for (int j = 0; j < 8; ++j)
        #pragma unroll
        for (int r = 0; r < 8; ++r) acc[j][r] = 0.f;

    #pragma unroll 4
    for (int d = 0; d < 64; ++d) {
        float kv[8];
        #pragma unroll
        for (int j = 0; j < 8; ++j)
            kv[j] = KTh[(size_t)d * cS + t + 256 * j];
        #pragma unroll
        for (int r = 0; r < 8; ++r) {
            const float q = Qf[r][d];
            #pragma unroll
            for (int j = 0; j < 8; ++j)
                acc[j][r] = fmaf(q, kv[j], acc[j][r]);
        }
    }
    #pragma unroll
    for (int j = 0; j < 8; ++j)
        #pragma unroll
        for (int r = 0; r < 8; ++r) {
            const float s = acc[j][r] * 0.125f;
            s16[r][t + 256 * j] = (unsigned short)(f2key(s) >> 16);
        }
    __syncthreads();

    // ---- phase B: per-row u16 radix select (need = 65) ----
    for (int i = t; i < 2048; i += 256) ((unsigned int*)hist)[i] = 0u;
    __syncthreads();
    #pragma unroll
    for (int r = 0; r < 8; ++r)
        #pragma unroll
        for (int j = 0; j < 8; ++j)
            atomicAdd(&hist[r][s16[r][t + 256 * j] >> 8], 1u);
    __syncthreads();
    if (t < 8) {
        int need = cKTOP + 1;   // 65
        int hb = 0;
        for (int bin = 255; bin >= 0; --bin) {
            const int c = (int)hist[t][bin];
            if (c >= need) { hb = bin; break; }
            need -= c;
        }
        t16[t] = hb << 8;
        rem[t] = need;
    }
    __syncthreads();
    for (int i = t; i < 2048; i += 256) ((unsigned int*)hist)[i] = 0u;
    __syncthreads();
    #pragma unroll
    for (int r = 0; r < 8; ++r) {
        const int hb = t16[r] >> 8;
        #pragma unroll
        for (int j = 0; j < 8; ++j) {
            const unsigned short v = s16[r][t + 256 * j];
            if ((v >> 8) == hb) atomicAdd(&hist[r][v & 255], 1u);
        }
    }
    __syncthreads();
    if (t < 8) {
        int need = rem[t];
        int lb = 0;
        for (int bin = 255; bin >= 0; --bin) {
            const int c = (int)hist[t][bin];
            if (c >= need) { lb = bin; break; }
            need -= c;
        }
        t16[t] |= lb;
    }
    __syncthreads();

    // ---- candidate scan: u16 >= T16 - 2 (margin for fp32 compute noise) ----
    #pragma unroll
    for (int r = 0; r < 8; ++r) {
        const int thr16 = max(t16[r] - 2, 0);
        #pragma unroll
        for (int j = 0; j < 8; ++j) {
            const int key = t + 256 * j;
            if ((int)s16[r][key] >= thr16) {
                const int slot = atomicAdd(&cnt[r], 1);
                if (slot < 128) cidx[r][slot] = (unsigned short)key;
            }
        }
    }
    __syncthreads();

    // ---- phase C: fp64 recompute of candidates (2 rows per wave) ----
    const int wv = t >> 6, lane = t & 63;
    for (int rr = wv * 2; rr < wv * 2 + 2; ++rr) {
        const int n = min(cnt[rr], 128);
        const double qd = (double)Qf[rr][lane];
        for (int j = 0; j < n; ++j) {
            const int key = cidx[rr][j];
            double prod = qd * (double)Ks[((size_t)(b * cS + key)) * cE + h64 + lane];
            #pragma unroll
            for (int off = 32; off >= 1; off >>= 1)
                prod += __shfl_xor(prod, off);
            if (lane == 0) cval[rr][j] = prod * 0.125;
        }
        if (lane == 0) ncs[rr] = n;
    }
    __syncthreads();

    // ---- ranking: T64 (rank 63), s65 (rank 64), m (rank 0) ----
    for (int rr = wv * 2; rr < wv * 2 + 2; ++rr) {
        const int n = ncs[rr];
        for (int j = lane; j < n; j += 64) {
            const double v = cval[rr][j];
            int rank = 0;
            for (int i = 0; i < n; ++i) rank += (cval[rr][i] > v) ? 1 : 0;
            if (rank == 0)  rowm[rr] = v;
            if (rank == 63) T64s[rr] = v;
            if (rank == 64) s65s[rr] = v;
        }
    }
    __syncthreads();

    // ---- weights: round-4 hedge formula on exact fp64 values ----
    for (int rr = wv * 2; rr < wv * 2 + 2; ++rr) {
        const int n = ncs[rr];
        const double T64 = T64s[rr], s65 = s65s[rr], m = rowm[rr];
        float za = 0.f;
        for (int j = lane; j < n; j += 64) {
            const double v = cval[rr][j];
            if (v >= T64) za += expf((float)(v - m));
        }
        #pragma unroll
        for (int off = 32; off >= 1; off >>= 1)
            za += __shfl_xor(za, off);
        const float g   = (float)(T64 - s65);
        const float gm  = fmaxf(g - 5e-7f, 0.f);
        const float wB  = 0.5f * erfcf(gm * (1.0f / 2.2e-6f));
        const float wA  = 1.f - wB;
        const float e64 = expf((float)(T64 - m));
        const float e65 = expf((float)(s65 - m));
        const float ZB  = za - e64 + e65;
        const float cIn = wA / za + wB / ZB;
        const float c64 = wA / za;
        const float c65 = wB / ZB;
        for (int j = lane; j < n; j += 64) {
            const double v = cval[rr][j];
            float c = 0.f;
            if (v > T64)       c = cIn;
            else if (v == T64) c = c64;
            else if (v == s65) c = c65;
            cw[rr][j] = (c != 0.f) ? c * expf((float)(v - m)) : 0.f;
        }
    }
    __syncthreads();

    // ---- phase D: sparse PV gather (lane = output dim) ----
    for (int rr = wv * 2; rr < wv * 2 + 2; ++rr) {
        const int n = ncs[rr];
        float o = 0.f;
        for (int j = 0; j < n; ++j) {
            const float w = cw[rr][j];
            const int key = cidx[rr][j];
            o = fmaf(w, V[((size_t)(b * cS + key)) * cE + h64 + lane], o);
        }
        O[((size_t)(b * cS + q0 + rr)) * cE + h64 + lane] = o;
    }
}

// ---------------------------------------------------------------------------
// Performer kernels (unchanged from round 4)
// ---------------------------------------------------------------------------
__global__ __launch_bounds__(256)
void perf_kv(const float* __restrict__ Kp, const float* __restrict__ Vp,
             const float* __restrict__ Wfeat,
             float* __restrict__ kv, float* __restrict__ z)
{
    __shared__ __align__(16) float Wf[64][68];
    __shared__ __align__(16) float Kt[64][68];
    __shared__ __align__(16) float Vt[64][68];
    __shared__ __align__(16) float Ph[64][68];
    const int t   = threadIdx.x;
    const int mc  = blockIdx.x;
    const int bh  = blockIdx.y;
    const int b   = bh >> 4;
    const int h64 = (bh & 15) * 64;
    const int m0  = mc * 64;

    for (int i = t; i < 64 * 64; i += 256) {
        const int d = i >> 6, mm = i & 63;
        Wf[d][mm] = Wfeat[d * cM + m0 + mm];
    }

    const int lr = t >> 4, lc = (t & 15) * 4;
    const int mph = t & 63, sph = t >> 6;
    const int d = t & 63, mrow = t >> 6;
    float akv[16];
    #pragma unroll
    for (int j = 0; j < 16; ++j) akv[j] = 0.f;
    float az = 0.f;

    for (int st = 0; st < 32; ++st) {
        const int s0 = st * 64;
        __syncthreads();
        #pragma unroll
        for (int i = 0; i < 4; ++i) {
            const int row = lr + 16 * i;
            const size_t base = ((size_t)(b * cS + s0 + row)) * cE + h64 + lc;
            *(float4*)&Kt[row][lc] = *(const float4*)&Kp[base];
            *(float4*)&Vt[row][lc] = *(const float4*)&Vp[base];
        }
        __syncthreads();
        #pragma unroll
        for (int j = 0; j < 16; ++j) {
            const int s = sph + 4 * j;
            float acc2 = 0.f;
            for (int dd = 0; dd < 64; ++dd)
                acc2 = fmaf(Kt[s][dd], Wf[dd][mph], acc2);
            Ph[s][mph] = fmaxf(acc2, 0.f) + cEPS;
        }
        __syncthreads();
        #pragma unroll
        for (int j = 0; j < 16; ++j) {
            const int mm = mrow + 4 * j;
            float a = akv[j];
            for (int ss = 0; ss < 64; ++ss)
                a = fmaf(Ph[ss][mm], Vt[ss][d], a);
            akv[j] = a;
        }
        if (t < 64) {
            float a = az;
            for (int ss = 0; ss < 64; ++ss) a += Ph[ss][t];
            az = a;
        }
    }
    #pragma unroll
    for (int j = 0; j < 16; ++j)
        kv[((size_t)bh * cM + m0 + mrow + 4 * j) * cD + d] = akv[j];
    if (t < 64) z[(size_t)bh * cM + m0 + t] = az;
}

__global__ __launch_bounds__(256)
void perf_numden(const float* __restrict__ Qp, const float* __restrict__ Wfeat,
                 const float* __restrict__ kv, const float* __restrict__ z,
                 float* __restrict__ Ap)
{
    __shared__ __align__(16) float Wf[64][68];
    __shared__ __align__(16) float Qt[64][68];
    __shared__ __align__(16) float KV[64][68];
    __shared__ __align__(16) float Ph[64][68];
    __shared__ float zl[64];
    __shared__ float denl[64];
    const int t   = threadIdx.x;
    const int stb = blockIdx.x;
    const int bh  = blockIdx.y;
    const int b   = bh >> 4;
    const int h64 = (bh & 15) * 64;
    const int s0  = stb * 64;
    const int lr = t >> 4, lc = (t & 15) * 4;
    #pragma unroll
    for (int i = 0; i < 4; ++i) {
        const int row = lr + 16 * i;
        *(float4*)&Qt[row][lc] =
            *(const float4*)&Qp[((size_t)(b * cS + s0 + row)) * cE + h64 + lc];
    }
    const int mph = t & 63, sph = t >> 6;
    const int d = t & 63, srow = t >> 6;
    float num[16];
    #pragma unroll
    for (int j = 0; j < 16; ++j) num[j] = 0.f;
    float denreg = 0.f;

    for (int mcI = 0; mcI < 4; ++mcI) {
        const int m0 = mcI * 64;
        __syncthreads();
        for (int i = t; i < 64 * 64; i += 256) {
            const int dd = i >> 6, mm = i & 63;
            Wf[dd][mm] = Wfeat[dd * cM + m0 + mm];
        }
        #pragma unroll
        for (int i = 0; i < 4; ++i) {
            const int row = lr + 16 * i;
            *(float4*)&KV[row][lc] =
                *(const float4*)&kv[((size_t)bh * cM + m0 + row) * cD + lc];
        }
        if (t < 64) zl[t] = z[(size_t)bh * cM + m0 + t];
        __syncthreads();
        #pragma unroll
        for (int j = 0; j < 16; ++j) {
            const int s = sph + 4 * j;
            float acc2 = 0.f;
            for (int dd = 0; dd < 64; ++dd)
                acc2 = fmaf(Qt[s][dd], Wf[dd][mph], acc2);
            Ph[s][mph] = fmaxf(acc2, 0.f) + cEPS;
        }
        __syncthreads();
        #pragma unroll
        for (int j = 0; j < 16; ++j) {
            const int s = srow + 4 * j;
            float a = num[j];
            for (int mm = 0; mm < 64; ++mm)
                a = fmaf(Ph[s][mm], KV[mm][d], a);
            num[j] = a;
        }
        if (t < 64) {
            float a = denreg;
            for (int mm = 0; mm < 64; ++mm) a = fmaf(Ph[t][mm], zl[mm], a);
            denreg = a;
        }
    }
    __syncthreads();
    if (t < 64) denl[t] = denreg + cEPS;
    __syncthreads();
    #pragma unroll
    for (int j = 0; j < 16; ++j) {
        const int s = srow + 4 * j;
        Ap[((size_t)(b * cS + s0 + s)) * cE + h64 + d] = num[j] / denl[s];
    }
}

// ---------------------------------------------------------------------------
// Gate (unchanged)
// ---------------------------------------------------------------------------
__global__ __launch_bounds__(256)
void gate_avg(const float* __restrict__ x, float* __restrict__ avg)
{
    const int i = blockIdx.x * 256 + threadIdx.x;
    const int b = i >> 10, e = i & 1023;
    double acc = 0.0;
    for (int s = 0; s < cS; ++s)
        acc += (double)x[((size_t)(b * cS + s)) * cE + e];
    avg[i] = (float)(acc / (double)cS);
}

__global__ void gate_final(const float* __restrict__ avg, const float* __restrict__ Wg,
                           const float* __restrict__ bg, float* __restrict__ gates)
{
    const int t = threadIdx.x;
    const int b = t >> 6, lane = t & 63;
    float l0 = 0.f, l1 = 0.f;
    for (int e = lane; e < cE; e += 64) {
        const float a = avg[b * cE + e];
        l0 = fmaf(a, Wg[e * 2 + 0], l0);
        l1 = fmaf(a, Wg[e * 2 + 1], l1);
    }
    for (int off = 32; off >= 1; off >>= 1) {
        l0 += __shfl_down(l0, off);
        l1 += __shfl_down(l1, off);
    }
    if (lane == 0) {
        l0 += bg[0]; l1 += bg[1];
        const float m = fmaxf(l0, l1);
        const float e0 = expf(l0 - m), e1 = expf(l1 - m);
        const float s = e0 + e1;
        gates[b * 2 + 0] = e0 / s;
        gates[b * 2 + 1] = e1 / s;
    }
}

// ---------------------------------------------------------------------------
// Fused epilogue (unchanged)
// ---------------------------------------------------------------------------
__global__ __launch_bounds__(256)
void out_gemm(const float* __restrict__ As_, const float* __restrict__ Ap_,
              const float* __restrict__ Wos, const float* __restrict__ Wop,
              const float* __restrict__ bos, const float* __restrict__ bop,
              const float* __restrict__ gates, float* __restrict__ out)
{
    __shared__ __align__(16) float A1[16][68];
    __shared__ __align__(16) float A2[16][68];
    __shared__ __align__(16) float B1[16][68];
    __shared__ __align__(16) float B2[16][68];
    const int t  = threadIdx.x;
    const int r0 = blockIdx.y * 64, c0 = blockIdx.x * 64;
    const int tm = t >> 4, tn = t & 15;
    const int b  = r0 >> 11;
    const float gs = gates[b * 2 + 0], gp = gates[b * 2 + 1];
    float acc[4][4] = {};
    const int ar = t >> 2, ak = (t & 3) * 4;
    const int bk = t >> 4, bc = (t & 15) * 4;
    for (int k0 = 0; k0 < cE; k0 += 16) {
        const float4 a1 = *(const float4*)&As_[((size_t)(r0 + ar)) * cE + k0 + ak];
        const float4 a2 = *(const float4*)&Ap_[((size_t)(r0 + ar)) * cE + k0 + ak];
        const float4 w1 = *(const float4*)&Wos[(size_t)(k0 + bk) * cE + c0 + bc];
        const float4 w2 = *(const float4*)&Wop[(size_t)(k0 + bk) * cE + c0 + bc];
        A1[ak + 0][ar] = a1.x * gs; A1[ak + 1][ar] = a1.y * gs;
        A1[ak + 2][ar] = a1.z * gs; A1[ak + 3][ar] = a1.w * gs;
        A2[ak + 0][ar] = a2.x * gp; A2[ak + 1][ar] = a2.y * gp;
        A2[ak + 2][ar] = a2.z * gp; A2[ak + 3][ar] = a2.w * gp;
        *(float4*)&B1[bk][bc] = w1;
        *(float4*)&B2[bk][bc] = w2;
        __syncthreads();
        #pragma unroll
        for (int kk = 0; kk < 16; ++kk) {
            const float4 a1v = *(const float4*)&A1[kk][tm * 4];
            const float4 b1v = *(const float4*)&B1[kk][tn * 4];
            const float4 a2v = *(const float4*)&A2[kk][tm * 4];
            const float4 b2v = *(const float4*)&B2[kk][tn * 4];
            const float av1[4] = {a1v.x, a1v.y, a1v.z, a1v.w};
            const float bw1[4] = {b1v.x, b1v.y, b1v.z, b1v.w};
            const float av2[4] = {a2v.x, a2v.y, a2v.z, a2v.w};
            const float bw2[4] = {b2v.x, b2v.y, b2v.z, b2v.w};
            #pragma unroll
            for (int i = 0; i < 4; ++i)
                #pragma unroll
                for (int j = 0; j < 4; ++j)
                    acc[i][j] = fmaf(av2[i], bw2[j], fmaf(av1[i], bw1[j], acc[i][j]));
        }
        __syncthreads();
    }
    #pragma unroll
    for (int i = 0; i < 4; ++i) {
        const int r = r0 + tm * 4 + i;
        const int c = c0 + tn * 4;
        float4 v;
        v.x = acc[i][0] + gs * bos[c + 0] + gp * bop[c + 0];
        v.y = acc[i][1] + gs * bos[c + 1] + gp * bop[c + 1];
        v.z = acc[i][2] + gs * bos[c + 2] + gp * bop[c + 2];
        v.w = acc[i][3] + gs * bos[c + 3] + gp * bop[c + 3];
        *(float4*)&out[(size_t)r * cE + c] = v;
    }
}

// ---------------------------------------------------------------------------
extern "C" void kernel_launch(void* const* d_in, const int* in_sizes, int n_in,
                              void* d_out, int out_size, void* d_ws, size_t ws_size,
                              hipStream_t stream)
{
    (void)in_sizes; (void)n_in; (void)out_size; (void)ws_size;
    const float* x     = (const float*)d_in[0];
    const float* Wq_s  = (const float*)d_in[1];
    const float* Wk_s  = (const float*)d_in[2];
    const float* Wv_s  = (const float*)d_in[3];
    const float* Wo_s  = (const float*)d_in[4];
    const float* bq_s  = (const float*)d_in[5];
    const float* bk_s  = (const float*)d_in[6];
    const float* bv_s  = (const float*)d_in[7];
    const float* bo_s  = (const float*)d_in[8];
    const float* Wq_p  = (const float*)d_in[9];
    const float* Wk_p  = (const float*)d_in[10];
    const float* Wv_p  = (const float*)d_in[11];
    const float* Wo_p  = (const float*)d_in[12];
    const float* bo_p  = (const float*)d_in[13];
    const float* Wfeat = (const float*)d_in[14];
    const float* Wg    = (const float*)d_in[15];
    const float* bg    = (const float*)d_in[16];

    float* ws = (float*)d_ws;
    const size_t NRE = (size_t)cB * cS * cE;
    float* Qs    = ws;              // later: Qp
    float* Ks    = Qs + NRE;        // later: Kp
    float* KsT   = Ks + NRE;        // later: Apout
    float* Vs    = KsT + NRE;       // later: Vp
    float* Asout = Vs + NRE;
    float* kvbuf = Asout + NRE;
    float* zbuf  = kvbuf + (size_t)cB * cH * cM * cD;
    float* avg   = zbuf + (size_t)cB * cH * cM;
    float* gates = avg + (size_t)cB * cE;

    // ---- sparse branch: BLAS-mimic fp32 q/k, fast hedged top-k ----
    gemm_qk_blas<<<dim3(16, 64), 256, 0, stream>>>(x, Wq_s, bq_s, Qs, cE, cE);
    gemm_qk_blas<<<dim3(16, 64), 256, 0, stream>>>(x, Wk_s, bk_s, Ks, cE, cE);
    gemm_f32<<<dim3(8, 32), 256, 0, stream>>>(x, Wv_s, bv_s, Vs, cE, cE);
    transpose_k<<<dim3(32, 32), 256, 0, stream>>>(Ks, KsT);
    sparse_attn<<<dim3(256, 32), 256, 0, stream>>>(Qs, KsT, Ks, Vs, Asout);

    // ---- performer branch (reuses buffers) ----
    float* Qp    = Qs;
    float* Kp    = Ks;
    float* Vp    = Vs;
    float* Apout = KsT;
    gemm_f32<<<dim3(8, 32), 256, 0, stream>>>(x, Wq_p, nullptr, Qp, cE, cE);
    gemm_f32<<<dim3(8, 32), 256, 0, stream>>>(x, Wk_p, nullptr, Kp, cE, cE);
    gemm_f32<<<dim3(8, 32), 256, 0, stream>>>(x, Wv_p, nullptr, Vp, cE, cE);
    perf_kv<<<dim3(4, 32), 256, 0, stream>>>(Kp, Vp, Wfeat, kvbuf, zbuf);
    perf_numden<<<dim3(32, 32), 256, 0, stream>>>(Qp, Wfeat, kvbuf, zbuf, Apout);

    // ---- gate + fused output ----
    gate_avg<<<dim3(8), 256, 0, stream>>>(x, avg);
    gate_final<<<dim3(1), 128, 0, stream>>>(avg, Wg, bg, gates);
    out_gemm<<<dim3(16, 64), 256, 0, stream>>>(Asout, Apout, Wo_s, Wo_p,
                                               bo_s, bo_p, gates, (float*)d_out);
}

// Round 6
// 3397.155 us; speedup vs baseline: 6.0439x; 2.5840x over previous
//
#include <hip/hip_runtime.h>

// ---------------------------------------------------------------------------
// HybridThoughtAwareAttention  (B=2,S=2048,E=1024,H=16,D=64,K_TOP=64,M=256)
// Round 6: performer branch rewritten (4x4 register tiles, float4 LDS, no
// spills; S-split partials). Sparse path & GEMMs identical to round 5.
// ---------------------------------------------------------------------------

constexpr int cB = 2, cS = 2048, cE = 1024, cH = 16, cD = 64, cKTOP = 64, cM = 256;
constexpr float cEPS = 1e-6f;

__device__ __forceinline__ unsigned int f2key(float f) {    // monotone f32->u32
    unsigned int u = __float_as_uint(f);
    return (u & 0x80000000u) ? ~u : (u | 0x80000000u);
}

// ---------------------------------------------------------------------------
// OpenBLAS-sgemm-mimicking fp32 GEMM for Qs/Ks (unchanged).
// ---------------------------------------------------------------------------
__global__ __launch_bounds__(256)
void gemm_qk_blas(const float* __restrict__ A,
                  const float* __restrict__ W,
                  const float* __restrict__ bias,
                  float* __restrict__ C, int K, int N)
{
    __shared__ __align__(16) float As[16][68];
    __shared__ __align__(16) float Bs[16][68];
    const int t  = threadIdx.x;
    const int r0 = blockIdx.y * 64;
    const int c0 = blockIdx.x * 64;
    const int tm = t >> 4, tn = t & 15;
    float pacc[4][4] = {};
    float cacc[4][4] = {};

    const int ar = t >> 2, ak = (t & 3) * 4;
    const int bk = t >> 4, bc = (t & 15) * 4;

    for (int k0 = 0; k0 < K; k0 += 16) {
        const float4 av = *(const float4*)(A + (size_t)(r0 + ar) * K + (k0 + ak));
        const float4 bv = *(const float4*)(W + (size_t)(k0 + bk) * N + (c0 + bc));
        As[ak + 0][ar] = av.x;
        As[ak + 1][ar] = av.y;
        As[ak + 2][ar] = av.z;
        As[ak + 3][ar] = av.w;
        *(float4*)&Bs[bk][bc] = bv;
        __syncthreads();
        #pragma unroll
        for (int kk = 0; kk < 16; ++kk) {
            const float4 a4 = *(const float4*)&As[kk][tm * 4];
            const float4 b4 = *(const float4*)&Bs[kk][tn * 4];
            const float a[4]  = {a4.x, a4.y, a4.z, a4.w};
            const float bb[4] = {b4.x, b4.y, b4.z, b4.w};
            #pragma unroll
            for (int i = 0; i < 4; ++i)
                #pragma unroll
                for (int j = 0; j < 4; ++j)
                    pacc[i][j] = fmaf(a[i], bb[j], pacc[i][j]);
        }
        __syncthreads();
        const int kn = k0 + 16;
        if (kn == 384 || kn == 768 || kn == K) {   // OpenBLAS KC=384 panel flush
            #pragma unroll
            for (int i = 0; i < 4; ++i)
                #pragma unroll
                for (int j = 0; j < 4; ++j) {
                    cacc[i][j] = cacc[i][j] + pacc[i][j];
                    pacc[i][j] = 0.f;
                }
        }
    }
    #pragma unroll
    for (int i = 0; i < 4; ++i) {
        const int r = r0 + tm * 4 + i;
        const int c = c0 + tn * 4;
        float4 v;
        v.x = cacc[i][0] + bias[c + 0];
        v.y = cacc[i][1] + bias[c + 1];
        v.z = cacc[i][2] + bias[c + 2];
        v.w = cacc[i][3] + bias[c + 3];
        *(float4*)&C[(size_t)r * N + c] = v;
    }
}

// ---------------------------------------------------------------------------
// fp32 GEMM (smooth path): 128x128 tile, BK=8. (unchanged)
// ---------------------------------------------------------------------------
__global__ __launch_bounds__(256)
void gemm_f32(const float* __restrict__ A,
              const float* __restrict__ W,
              const float* __restrict__ bias,
              float* __restrict__ C, int K, int N)
{
    __shared__ __align__(16) float As[8][132];
    __shared__ __align__(16) float Bs[8][132];
    const int t  = threadIdx.x;
    const int r0 = blockIdx.y * 128;
    const int c0 = blockIdx.x * 128;
    const int tm = t >> 4, tn = t & 15;
    float acc[8][8] = {};

    const int ar = t >> 1;
    const int ak = (t & 1) * 4;
    const int bk = t >> 5;
    const int bc = (t & 31) * 4;

    for (int k0 = 0; k0 < K; k0 += 8) {
        const float4 av = *(const float4*)(A + (size_t)(r0 + ar) * K + (k0 + ak));
        const float4 bv = *(const float4*)(W + (size_t)(k0 + bk) * N + (c0 + bc));
        As[ak + 0][ar] = av.x;
        As[ak + 1][ar] = av.y;
        As[ak + 2][ar] = av.z;
        As[ak + 3][ar] = av.w;
        *(float4*)&Bs[bk][bc] = bv;
        __syncthreads();
        #pragma unroll
        for (int kk = 0; kk < 8; ++kk) {
            const float4 a0 = *(const float4*)&As[kk][tm * 4];
            const float4 a1 = *(const float4*)&As[kk][tm * 4 + 64];
            const float4 b0 = *(const float4*)&Bs[kk][tn * 4];
            const float4 b1 = *(const float4*)&Bs[kk][tn * 4 + 64];
            const float a[8]  = {a0.x, a0.y, a0.z, a0.w, a1.x, a1.y, a1.z, a1.w};
            const float bb[8] = {b0.x, b0.y, b0.z, b0.w, b1.x, b1.y, b1.z, b1.w};
            #pragma unroll
            for (int i = 0; i < 8; ++i)
                #pragma unroll
                for (int j = 0; j < 8; ++j)
                    acc[i][j] = fmaf(a[i], bb[j], acc[i][j]);
        }
        __syncthreads();
    }
    #pragma unroll
    for (int ih = 0; ih < 2; ++ih) {
        #pragma unroll
        for (int ii = 0; ii < 4; ++ii) {
            const int r = r0 + ih * 64 + tm * 4 + ii;
            const int i = ih * 4 + ii;
            #pragma unroll
            for (int jh = 0; jh < 2; ++jh) {
                const int c = c0 + jh * 64 + tn * 4;
                float4 v;
                v.x = acc[i][jh * 4 + 0];
                v.y = acc[i][jh * 4 + 1];
                v.z = acc[i][jh * 4 + 2];
                v.w = acc[i][jh * 4 + 3];
                if (bias) {
                    v.x += bias[c + 0]; v.y += bias[c + 1];
                    v.z += bias[c + 2]; v.w += bias[c + 3];
                }
                *(float4*)&C[(size_t)r * N + c] = v;
            }
        }
    }
}

// ---------------------------------------------------------------------------
// K transpose: (B,S,H,D) fp32 -> (B,H,D,S)  (unchanged)
// ---------------------------------------------------------------------------
__global__ __launch_bounds__(256)
void transpose_k(const float* __restrict__ Ks, float* __restrict__ KsT)
{
    __shared__ float tile[64][65];
    const int t  = threadIdx.x;
    const int bh = blockIdx.y;
    const int b  = bh >> 4;
    const int h64 = (bh & 15) * 64;
    const int s0 = blockIdx.x * 64;
    const int sr = t >> 4;
    const int d4 = (t & 15) * 4;
    #pragma unroll
    for (int i = 0; i < 4; ++i) {
        const int s = sr + 16 * i;
        float4 v = *(const float4*)&Ks[((size_t)(b * cS + s0 + s)) * cE + h64 + d4];
        tile[s][d4 + 0] = v.x; tile[s][d4 + 1] = v.y;
        tile[s][d4 + 2] = v.z; tile[s][d4 + 3] = v.w;
    }
    __syncthreads();
    const int s4 = (t & 15) * 4;
    #pragma unroll
    for (int i = 0; i < 4; ++i) {
        const int d = (t >> 4) + 16 * i;
        float4 w;
        w.x = tile[s4 + 0][d]; w.y = tile[s4 + 1][d];
        w.z = tile[s4 + 2][d]; w.w = tile[s4 + 3][d];
        *(float4*)&KsT[((size_t)(bh * 64 + d)) * cS + s0 + s4] = w;
    }
}

// ---------------------------------------------------------------------------
// Sparse attention (unchanged from round 5).
// ---------------------------------------------------------------------------
__global__ __launch_bounds__(256, 2)
void sparse_attn(const float* __restrict__ Q, const float* __restrict__ KT,
                 const float* __restrict__ Ks, const float* __restrict__ V,
                 float* __restrict__ O)
{
    __shared__ unsigned short s16[8][2048];      // 32 KB quantized scores
    __shared__ float Qf[8][64];                  // 2 KB
    __shared__ unsigned int hist[8][256];        // 8 KB
    __shared__ unsigned short cidx[8][128];      // 2 KB
    __shared__ double cval[8][128];              // 8 KB
    __shared__ float cw[8][128];                 // 4 KB
    __shared__ int cnt[8];
    __shared__ int rem[8];
    __shared__ int t16[8];
    __shared__ int ncs[8];
    __shared__ double T64s[8], s65s[8], rowm[8];

    const int t   = threadIdx.x;
    const int bh  = blockIdx.y;
    const int b   = bh >> 4;
    const int h64 = (bh & 15) * 64;
    const int q0  = blockIdx.x * 8;

    if (t < 128) {
        const int r = t >> 4, c4 = (t & 15) * 4;
        *(float4*)&Qf[r][c4] =
            *(const float4*)&Q[((size_t)(b * cS + q0 + r)) * cE + h64 + c4];
    }
    if (t < 8) cnt[t] = 0;
    __syncthreads();

    // ---- phase A: fp32 scores, 8 keys x 8 rows per thread ----
    const float* KTh = KT + (size_t)bh * 64 * cS;
    float acc[8][8];
    #pragma unroll
    for (int j = 0; j < 8; ++j)
        #pragma unroll
        for (int r = 0; r < 8; ++r) acc[j][r] = 0.f;

    #pragma unroll 4
    for (int d = 0; d < 64; ++d) {
        float kv[8];
        #pragma unroll
        for (int j = 0; j < 8; ++j)
            kv[j] = KTh[(size_t)d * cS + t + 256 * j];
        #pragma unroll
        for (int r = 0; r < 8; ++r) {
            const float q = Qf[r][d];
            #pragma unroll
            for (int j = 0; j < 8; ++j)
                acc[j][r] = fmaf(q, kv[j], acc[j][r]);
        }
    }
    #pragma unroll
    for (int j = 0; j < 8; ++j)
        #pragma unroll
        for (int r = 0; r < 8; ++r) {
            const float s = acc[j][r] * 0.125f;
            s16[r][t + 256 * j] = (unsigned short)(f2key(s) >> 16);
        }
    __syncthreads();

    // ---- phase B: per-row u16 radix select (need = 65) ----
    for (int i = t; i < 2048; i += 256) ((unsigned int*)hist)[i] = 0u;
    __syncthreads();
    #pragma unroll
    for (int r = 0; r < 8; ++r)
        #pragma unroll
        for (int j = 0; j < 8; ++j)
            atomicAdd(&hist[r][s16[r][t + 256 * j] >> 8], 1u);
    __syncthreads();
    if (t < 8) {
        int need = cKTOP + 1;   // 65
        int hb = 0;
        for (int bin = 255; bin >= 0; --bin) {
            const int c = (int)hist[t][bin];
            if (c >= need) { hb = bin; break; }
            need -= c;
        }
        t16[t] = hb << 8;
        rem[t] = need;
    }
    __syncthreads();
    for (int i = t; i < 2048; i += 256) ((unsigned int*)hist)[i] = 0u;
    __syncthreads();
    #pragma unroll
    for (int r = 0; r < 8; ++r) {
        const int hb = t16[r] >> 8;
        #pragma unroll
        for (int j = 0; j < 8; ++j) {
            const unsigned short v = s16[r][t + 256 * j];
            if ((v >> 8) == hb) atomicAdd(&hist[r][v & 255], 1u);
        }
    }
    __syncthreads();
    if (t < 8) {
        int need = rem[t];
        int lb = 0;
        for (int bin = 255; bin >= 0; --bin) {
            const int c = (int)hist[t][bin];
            if (c >= need) { lb = bin; break; }
            need -= c;
        }
        t16[t] |= lb;
    }
    __syncthreads();

    // ---- candidate scan: u16 >= T16 - 2 (margin for fp32 compute noise) ----
    #pragma unroll
    for (int r = 0; r < 8; ++r) {
        const int thr16 = max(t16[r] - 2, 0);
        #pragma unroll
        for (int j = 0; j < 8; ++j) {
            const int key = t + 256 * j;
            if ((int)s16[r][key] >= thr16) {
                const int slot = atomicAdd(&cnt[r], 1);
                if (slot < 128) cidx[r][slot] = (unsigned short)key;
            }
        }
    }
    __syncthreads();

    // ---- phase C: fp64 recompute of candidates (2 rows per wave) ----
    const int wv = t >> 6, lane = t & 63;
    for (int rr = wv * 2; rr < wv * 2 + 2; ++rr) {
        const int n = min(cnt[rr], 128);
        const double qd = (double)Qf[rr][lane];
        for (int j = 0; j < n; ++j) {
            const int key = cidx[rr][j];
            double prod = qd * (double)Ks[((size_t)(b * cS + key)) * cE + h64 + lane];
            #pragma unroll
            for (int off = 32; off >= 1; off >>= 1)
                prod += __shfl_xor(prod, off);
            if (lane == 0) cval[rr][j] = prod * 0.125;
        }
        if (lane == 0) ncs[rr] = n;
    }
    __syncthreads();

    // ---- ranking: T64 (rank 63), s65 (rank 64), m (rank 0) ----
    for (int rr = wv * 2; rr < wv * 2 + 2; ++rr) {
        const int n = ncs[rr];
        for (int j = lane; j < n; j += 64) {
            const double v = cval[rr][j];
            int rank = 0;
            for (int i = 0; i < n; ++i) rank += (cval[rr][i] > v) ? 1 : 0;
            if (rank == 0)  rowm[rr] = v;
            if (rank == 63) T64s[rr] = v;
            if (rank == 64) s65s[rr] = v;
        }
    }
    __syncthreads();

    // ---- weights: hedge formula on exact fp64 values ----
    for (int rr = wv * 2; rr < wv * 2 + 2; ++rr) {
        const int n = ncs[rr];
        const double T64 = T64s[rr], s65 = s65s[rr], m = rowm[rr];
        float za = 0.f;
        for (int j = lane; j < n; j += 64) {
            const double v = cval[rr][j];
            if (v >= T64) za += expf((float)(v - m));
        }
        #pragma unroll
        for (int off = 32; off >= 1; off >>= 1)
            za += __shfl_xor(za, off);
        const float g   = (float)(T64 - s65);
        const float gm  = fmaxf(g - 5e-7f, 0.f);
        const float wB  = 0.5f * erfcf(gm * (1.0f / 2.2e-6f));
        const float wA  = 1.f - wB;
        const float e64 = expf((float)(T64 - m));
        const float e65 = expf((float)(s65 - m));
        const float ZB  = za - e64 + e65;
        const float cIn = wA / za + wB / ZB;
        const float c64 = wA / za;
        const float c65 = wB / ZB;
        for (int j = lane; j < n; j += 64) {
            const double v = cval[rr][j];
            float c = 0.f;
            if (v > T64)       c = cIn;
            else if (v == T64) c = c64;
            else if (v == s65) c = c65;
            cw[rr][j] = (c != 0.f) ? c * expf((float)(v - m)) : 0.f;
        }
    }
    __syncthreads();

    // ---- phase D: sparse PV gather (lane = output dim) ----
    for (int rr = wv * 2; rr < wv * 2 + 2; ++rr) {
        const int n = ncs[rr];
        float o = 0.f;
        for (int j = 0; j < n; ++j) {
            const float w = cw[rr][j];
            const int key = cidx[rr][j];
            o = fmaf(w, V[((size_t)(b * cS + key)) * cE + h64 + lane], o);
        }
        O[((size_t)(b * cS + q0 + rr)) * cE + h64 + lane] = o;
    }
}

// ---------------------------------------------------------------------------
// Performer kv (REWRITTEN): grid (mc*2+sc? -> x = sc*4+mc, bh). Each block:
// one m-chunk of 64, one s-half of 1024. 4x4 register tiles, float4 LDS.
// kvpart[sc][bh][m][d], zpart[sc][bh][m].
// ---------------------------------------------------------------------------
__global__ __launch_bounds__(256)
void perf_kv(const float* __restrict__ Kp, const float* __restrict__ Vp,
             const float* __restrict__ Wfeat,
             float* __restrict__ kvpart, float* __restrict__ zpart)
{
    __shared__ __align__(16) float Wf[64][68];
    __shared__ __align__(16) float Kt[64][68];
    __shared__ __align__(16) float Vt[64][68];
    __shared__ __align__(16) float Ph[64][68];
    const int t    = threadIdx.x;
    const int mc   = blockIdx.x & 3;
    const int sc   = blockIdx.x >> 2;          // 0 or 1
    const int bh   = blockIdx.y;
    const int b    = bh >> 4;
    const int h64  = (bh & 15) * 64;
    const int m0   = mc * 64;
    const int sbase = sc * 1024;

    // Wf[d][m] (64x64 chunk), float4 coalesced
    #pragma unroll
    for (int i = 0; i < 4; ++i) {
        const int lin = t + 256 * i;           // 0..1023
        const int d   = lin >> 4;
        const int m4  = (lin & 15) * 4;
        *(float4*)&Wf[d][m4] = *(const float4*)&Wfeat[d * cM + m0 + m4];
    }

    const int tm = t >> 4, tn = t & 15;
    const int sr = tm * 4;                     // phi rows / kv m-rows
    const int cn = tn * 4;                     // phi m-cols / kv d-cols
    float akv[4][4] = {};
    float az = 0.f;

    for (int st = 0; st < 16; ++st) {
        const int s0g = sbase + st * 64;
        __syncthreads();                       // Kt/Vt/Ph free (covers Wf on iter 0)
        #pragma unroll
        for (int i = 0; i < 4; ++i) {
            const int row = tm + 16 * i;
            const size_t base = ((size_t)(b * cS + s0g + row)) * cE + h64 + cn;
            *(float4*)&Kt[row][cn] = *(const float4*)&Kp[base];
            *(float4*)&Vt[row][cn] = *(const float4*)&Vp[base];
        }
        __syncthreads();
        // phi: thread computes Ph[sr..sr+3][cn..cn+3]
        float4 p0 = {0,0,0,0}, p1 = {0,0,0,0}, p2 = {0,0,0,0}, p3 = {0,0,0,0};
        #pragma unroll 8
        for (int d = 0; d < 64; ++d) {
            const float4 wv = *(const float4*)&Wf[d][cn];
            const float k0 = Kt[sr + 0][d], k1 = Kt[sr + 1][d];
            const float k2 = Kt[sr + 2][d], k3 = Kt[sr + 3][d];
            p0.x = fmaf(k0, wv.x, p0.x); p0.y = fmaf(k0, wv.y, p0.y);
            p0.z = fmaf(k0, wv.z, p0.z); p0.w = fmaf(k0, wv.w, p0.w);
            p1.x = fmaf(k1, wv.x, p1.x); p1.y = fmaf(k1, wv.y, p1.y);
            p1.z = fmaf(k1, wv.z, p1.z); p1.w = fmaf(k1, wv.w, p1.w);
            p2.x = fmaf(k2, wv.x, p2.x); p2.y = fmaf(k2, wv.y, p2.y);
            p2.z = fmaf(k2, wv.z, p2.z); p2.w = fmaf(k2, wv.w, p2.w);
            p3.x = fmaf(k3, wv.x, p3.x); p3.y = fmaf(k3, wv.y, p3.y);
            p3.z = fmaf(k3, wv.z, p3.z); p3.w = fmaf(k3, wv.w, p3.w);
        }
        p0.x = fmaxf(p0.x, 0.f) + cEPS; p0.y = fmaxf(p0.y, 0.f) + cEPS;
        p0.z = fmaxf(p0.z, 0.f) + cEPS; p0.w = fmaxf(p0.w, 0.f) + cEPS;
        p1.x = fmaxf(p1.x, 0.f) + cEPS; p1.y = fmaxf(p1.y, 0.f) + cEPS;
        p1.z = fmaxf(p1.z, 0.f) + cEPS; p1.w = fmaxf(p1.w, 0.f) + cEPS;
        p2.x = fmaxf(p2.x, 0.f) + cEPS; p2.y = fmaxf(p2.y, 0.f) + cEPS;
        p2.z = fmaxf(p2.z, 0.f) + cEPS; p2.w = fmaxf(p2.w, 0.f) + cEPS;
        p3.x = fmaxf(p3.x, 0.f) + cEPS; p3.y = fmaxf(p3.y, 0.f) + cEPS;
        p3.z = fmaxf(p3.z, 0.f) + cEPS; p3.w = fmaxf(p3.w, 0.f) + cEPS;
        *(float4*)&Ph[sr + 0][cn] = p0;
        *(float4*)&Ph[sr + 1][cn] = p1;
        *(float4*)&Ph[sr + 2][cn] = p2;
        *(float4*)&Ph[sr + 3][cn] = p3;
        __syncthreads();
        // kv accumulate: m-rows sr.., d-cols cn..
        #pragma unroll 8
        for (int ss = 0; ss < 64; ++ss) {
            const float4 pv = *(const float4*)&Ph[ss][sr];
            const float4 vv = *(const float4*)&Vt[ss][cn];
            akv[0][0] = fmaf(pv.x, vv.x, akv[0][0]); akv[0][1] = fmaf(pv.x, vv.y, akv[0][1]);
            akv[0][2] = fmaf(pv.x, vv.z, akv[0][2]); akv[0][3] = fmaf(pv.x, vv.w, akv[0][3]);
            akv[1][0] = fmaf(pv.y, vv.x, akv[1][0]); akv[1][1] = fmaf(pv.y, vv.y, akv[1][1]);
            akv[1][2] = fmaf(pv.y, vv.z, akv[1][2]); akv[1][3] = fmaf(pv.y, vv.w, akv[1][3]);
            akv[2][0] = fmaf(pv.z, vv.x, akv[2][0]); akv[2][1] = fmaf(pv.z, vv.y, akv[2][1]);
            akv[2][2] = fmaf(pv.z, vv.z, akv[2][2]); akv[2][3] = fmaf(pv.z, vv.w, akv[2][3]);
            akv[3][0] = fmaf(pv.w, vv.x, akv[3][0]); akv[3][1] = fmaf(pv.w, vv.y, akv[3][1]);
            akv[3][2] = fmaf(pv.w, vv.z, akv[3][2]); akv[3][3] = fmaf(pv.w, vv.w, akv[3][3]);
        }
        if (t < 64) {
            float a = 0.f;
            #pragma unroll 8
            for (int ss = 0; ss < 64; ++ss) a += Ph[ss][t];
            az += a;
        }
    }
    const size_t obase = ((size_t)(sc * 32 + bh)) * cM + m0;
    #pragma unroll
    for (int i = 0; i < 4; ++i) {
        float4 v; v.x = akv[i][0]; v.y = akv[i][1]; v.z = akv[i][2]; v.w = akv[i][3];
        *(float4*)&kvpart[(obase + sr + i) * cD + cn] = v;
    }
    if (t < 64) zpart[obase + t] = az;
}

// ---------------------------------------------------------------------------
// Performer num/den (REWRITTEN): grid (32 s-tiles, 32 bh). 4x4 register tile;
// reduces the two kv/z partials at load.
// ---------------------------------------------------------------------------
__global__ __launch_bounds__(256)
void perf_numden(const float* __restrict__ Qp, const float* __restrict__ Wfeat,
                 const float* __restrict__ kvpart, const float* __restrict__ zpart,
                 float* __restrict__ Ap)
{
    __shared__ __align__(16) float Wf[64][68];
    __shared__ __align__(16) float Qt[64][68];
    __shared__ __align__(16) float KV[64][68];
    __shared__ __align__(16) float Ph[64][68];
    __shared__ __align__(16) float zl[64];
    __shared__ float den[64];
    const int t   = threadIdx.x;
    const int stb = blockIdx.x;
    const int bh  = blockIdx.y;
    const int b   = bh >> 4;
    const int h64 = (bh & 15) * 64;
    const int s0  = stb * 64;
    const int tm  = t >> 4, tn = t & 15;
    const int sr  = tm * 4, cn = tn * 4;

    #pragma unroll
    for (int i = 0; i < 4; ++i) {
        const int row = tm + 16 * i;
        *(float4*)&Qt[row][cn] =
            *(const float4*)&Qp[((size_t)(b * cS + s0 + row)) * cE + h64 + cn];
    }

    float num[4][4] = {};
    float dacc = 0.f;

    for (int mc = 0; mc < 4; ++mc) {
        const int m0 = mc * 64;
        __syncthreads();                   // Wf/KV/Ph free (covers Qt on iter 0)
        #pragma unroll
        for (int i = 0; i < 4; ++i) {
            const int lin = t + 256 * i;
            const int d   = lin >> 4;
            const int m4  = (lin & 15) * 4;
            *(float4*)&Wf[d][m4] = *(const float4*)&Wfeat[d * cM + m0 + m4];
        }
        #pragma unroll
        for (int i = 0; i < 4; ++i) {
            const int row = tm + 16 * i;
            const size_t o0 = ((size_t)bh * cM + m0 + row) * cD + cn;
            const size_t o1 = ((size_t)(32 + bh) * cM + m0 + row) * cD + cn;
            const float4 a = *(const float4*)&kvpart[o0];
            const float4 c = *(const float4*)&kvpart[o1];
            float4 v; v.x = a.x + c.x; v.y = a.y + c.y; v.z = a.z + c.z; v.w = a.w + c.w;
            *(float4*)&KV[row][cn] = v;
        }
        if (t < 64)
            zl[t] = zpart[(size_t)bh * cM + m0 + t] + zpart[(size_t)(32 + bh) * cM + m0 + t];
        __syncthreads();
        // phi over Qt
        float4 p0 = {0,0,0,0}, p1 = {0,0,0,0}, p2 = {0,0,0,0}, p3 = {0,0,0,0};
        #pragma unroll 8
        for (int d = 0; d < 64; ++d) {
            const float4 wv = *(const float4*)&Wf[d][cn];
            const float q0 = Qt[sr + 0][d], q1 = Qt[sr + 1][d];
            const float q2 = Qt[sr + 2][d], q3 = Qt[sr + 3][d];
            p0.x = fmaf(q0, wv.x, p0.x); p0.y = fmaf(q0, wv.y, p0.y);
            p0.z = fmaf(q0, wv.z, p0.z); p0.w = fmaf(q0, wv.w, p0.w);
            p1.x = fmaf(q1, wv.x, p1.x); p1.y = fmaf(q1, wv.y, p1.y);
            p1.z = fmaf(q1, wv.z, p1.z); p1.w = fmaf(q1, wv.w, p1.w);
            p2.x = fmaf(q2, wv.x, p2.x); p2.y = fmaf(q2, wv.y, p2.y);
            p2.z = fmaf(q2, wv.z, p2.z); p2.w = fmaf(q2, wv.w, p2.w);
            p3.x = fmaf(q3, wv.x, p3.x); p3.y = fmaf(q3, wv.y, p3.y);
            p3.z = fmaf(q3, wv.z, p3.z); p3.w = fmaf(q3, wv.w, p3.w);
        }
        p0.x = fmaxf(p0.x, 0.f) + cEPS; p0.y = fmaxf(p0.y, 0.f) + cEPS;
        p0.z = fmaxf(p0.z, 0.f) + cEPS; p0.w = fmaxf(p0.w, 0.f) + cEPS;
        p1.x = fmaxf(p1.x, 0.f) + cEPS; p1.y = fmaxf(p1.y, 0.f) + cEPS;
        p1.z = fmaxf(p1.z, 0.f) + cEPS; p1.w = fmaxf(p1.w, 0.f) + cEPS;
        p2.x = fmaxf(p2.x, 0.f) + cEPS; p2.y = fmaxf(p2.y, 0.f) + cEPS;
        p2.z = fmaxf(p2.z, 0.f) + cEPS; p2.w = fmaxf(p2.w, 0.f) + cEPS;
        p3.x = fmaxf(p3.x, 0.f) + cEPS; p3.y = fmaxf(p3.y, 0.f) + cEPS;
        p3.z = fmaxf(p3.z, 0.f) + cEPS; p3.w = fmaxf(p3.w, 0.f) + cEPS;
        *(float4*)&Ph[sr + 0][cn] = p0;
        *(float4*)&Ph[sr + 1][cn] = p1;
        *(float4*)&Ph[sr + 2][cn] = p2;
        *(float4*)&Ph[sr + 3][cn] = p3;
        __syncthreads();
        // num accumulate: s-rows sr.., d-cols cn..
        #pragma unroll 8
        for (int mm = 0; mm < 64; ++mm) {
            const float4 kvv = *(const float4*)&KV[mm][cn];
            const float a0 = Ph[sr + 0][mm], a1 = Ph[sr + 1][mm];
            const float a2 = Ph[sr + 2][mm], a3 = Ph[sr + 3][mm];
            num[0][0] = fmaf(a0, kvv.x, num[0][0]); num[0][1] = fmaf(a0, kvv.y, num[0][1]);
            num[0][2] = fmaf(a0, kvv.z, num[0][2]); num[0][3] = fmaf(a0, kvv.w, num[0][3]);
            num[1][0] = fmaf(a1, kvv.x, num[1][0]); num[1][1] = fmaf(a1, kvv.y, num[1][1]);
            num[1][2] = fmaf(a1, kvv.z, num[1][2]); num[1][3] = fmaf(a1, kvv.w, num[1][3]);
            num[2][0] = fmaf(a2, kvv.x, num[2][0]); num[2][1] = fmaf(a2, kvv.y, num[2][1]);
            num[2][2] = fmaf(a2, kvv.z, num[2][2]); num[2][3] = fmaf(a2, kvv.w, num[2][3]);
            num[3][0] = fmaf(a3, kvv.x, num[3][0]); num[3][1] = fmaf(a3, kvv.y, num[3][1]);
            num[3][2] = fmaf(a3, kvv.z, num[3][2]); num[3][3] = fmaf(a3, kvv.w, num[3][3]);
        }
        if (t < 64) {
            float a = 0.f;
            #pragma unroll
            for (int m4 = 0; m4 < 64; m4 += 4) {
                const float4 ph = *(const float4*)&Ph[t][m4];
                const float4 zz = *(const float4*)&zl[m4];
                a = fmaf(ph.x, zz.x, a); a = fmaf(ph.y, zz.y, a);
                a = fmaf(ph.z, zz.z, a); a = fmaf(ph.w, zz.w, a);
            }
            dacc += a;
        }
    }
    __syncthreads();
    if (t < 64) den[t] = dacc + cEPS;
    __syncthreads();
    #pragma unroll
    for (int i = 0; i < 4; ++i) {
        const float di = 1.f / den[sr + i];
        float4 v;
        v.x = num[i][0] * di; v.y = num[i][1] * di;
        v.z = num[i][2] * di; v.w = num[i][3] * di;
        *(float4*)&Ap[((size_t)(b * cS + s0 + sr + i)) * cE + h64 + cn] = v;
    }
}

// ---------------------------------------------------------------------------
// Gate: S-split partial sums (f64), then reduce in gate_final.
// ---------------------------------------------------------------------------
__global__ __launch_bounds__(256)
void gate_avg(const float* __restrict__ x, double* __restrict__ avgpart)
{
    const int i  = blockIdx.x * 256 + threadIdx.x;    // 0..2047: (b,e)
    const int sc = blockIdx.y;                        // 0..15
    const int b  = i >> 10, e = i & 1023;
    double acc = 0.0;
    const int sEnd = sc * 128 + 128;
    for (int s = sc * 128; s < sEnd; ++s)
        acc += (double)x[((size_t)(b * cS + s)) * cE + e];
    avgpart[(size_t)sc * 2048 + i] = acc;
}

__global__ void gate_final(const double* __restrict__ avgpart, const float* __restrict__ Wg,
                           const float* __restrict__ bg, float* __restrict__ gates)
{
    const int t = threadIdx.x;
    const int b = t >> 6, lane = t & 63;
    float l0 = 0.f, l1 = 0.f;
    for (int e = lane; e < cE; e += 64) {
        double s = 0.0;
        #pragma unroll
        for (int sc = 0; sc < 16; ++sc)
            s += avgpart[(size_t)sc * 2048 + b * 1024 + e];
        const float a = (float)(s / (double)cS);
        l0 = fmaf(a, Wg[e * 2 + 0], l0);
        l1 = fmaf(a, Wg[e * 2 + 1], l1);
    }
    for (int off = 32; off >= 1; off >>= 1) {
        l0 += __shfl_down(l0, off);
        l1 += __shfl_down(l1, off);
    }
    if (lane == 0) {
        l0 += bg[0]; l1 += bg[1];
        const float m = fmaxf(l0, l1);
        const float e0 = expf(l0 - m), e1 = expf(l1 - m);
        const float s = e0 + e1;
        gates[b * 2 + 0] = e0 / s;
        gates[b * 2 + 1] = e1 / s;
    }
}

// ---------------------------------------------------------------------------
// Fused epilogue (unchanged)
// ---------------------------------------------------------------------------
__global__ __launch_bounds__(256)
void out_gemm(const float* __restrict__ As_, const float* __restrict__ Ap_,
              const float* __restrict__ Wos, const float* __restrict__ Wop,
              const float* __restrict__ bos, const float* __restrict__ bop,
              const float* __restrict__ gates, float* __restrict__ out)
{
    __shared__ __align__(16) float A1[16][68];
    __shared__ __align__(16) float A2[16][68];
    __shared__ __align__(16) float B1[16][68];
    __shared__ __align__(16) float B2[16][68];
    const int t  = threadIdx.x;
    const int r0 = blockIdx.y * 64, c0 = blockIdx.x * 64;
    const int tm = t >> 4, tn = t & 15;
    const int b  = r0 >> 11;
    const float gs = gates[b * 2 + 0], gp = gates[b * 2 + 1];
    float acc[4][4] = {};
    const int ar = t >> 2, ak = (t & 3) * 4;
    const int bk = t >> 4, bc = (t & 15) * 4;
    for (int k0 = 0; k0 < cE; k0 += 16) {
        const float4 a1 = *(const float4*)&As_[((size_t)(r0 + ar)) * cE + k0 + ak];
        const float4 a2 = *(const float4*)&Ap_[((size_t)(r0 + ar)) * cE + k0 + ak];
        const float4 w1 = *(const float4*)&Wos[(size_t)(k0 + bk) * cE + c0 + bc];
        const float4 w2 = *(const float4*)&Wop[(size_t)(k0 + bk) * cE + c0 + bc];
        A1[ak + 0][ar] = a1.x * gs; A1[ak + 1][ar] = a1.y * gs;
        A1[ak + 2][ar] = a1.z * gs; A1[ak + 3][ar] = a1.w * gs;
        A2[ak + 0][ar] = a2.x * gp; A2[ak + 1][ar] = a2.y * gp;
        A2[ak + 2][ar] = a2.z * gp; A2[ak + 3][ar] = a2.w * gp;
        *(float4*)&B1[bk][bc] = w1;
        *(float4*)&B2[bk][bc] = w2;
        __syncthreads();
        #pragma unroll
        for (int kk = 0; kk < 16; ++kk) {
            const float4 a1v = *(const float4*)&A1[kk][tm * 4];
            const float4 b1v = *(const float4*)&B1[kk][tn * 4];
            const float4 a2v = *(const float4*)&A2[kk][tm * 4];
            const float4 b2v = *(const float4*)&B2[kk][tn * 4];
            const float av1[4] = {a1v.x, a1v.y, a1v.z, a1v.w};
            const float bw1[4] = {b1v.x, b1v.y, b1v.z, b1v.w};
            const float av2[4] = {a2v.x, a2v.y, a2v.z, a2v.w};
            const float bw2[4] = {b2v.x, b2v.y, b2v.z, b2v.w};
            #pragma unroll
            for (int i = 0; i < 4; ++i)
                #pragma unroll
                for (int j = 0; j < 4; ++j)
                    acc[i][j] = fmaf(av2[i], bw2[j], fmaf(av1[i], bw1[j], acc[i][j]));
        }
        __syncthreads();
    }
    #pragma unroll
    for (int i = 0; i < 4; ++i) {
        const int r = r0 + tm * 4 + i;
        const int c = c0 + tn * 4;
        float4 v;
        v.x = acc[i][0] + gs * bos[c + 0] + gp * bop[c + 0];
        v.y = acc[i][1] + gs * bos[c + 1] + gp * bop[c + 1];
        v.z = acc[i][2] + gs * bos[c + 2] + gp * bop[c + 2];
        v.w = acc[i][3] + gs * bos[c + 3] + gp * bop[c + 3];
        *(float4*)&out[(size_t)r * cE + c] = v;
    }
}

// ---------------------------------------------------------------------------
extern "C" void kernel_launch(void* const* d_in, const int* in_sizes, int n_in,
                              void* d_out, int out_size, void* d_ws, size_t ws_size,
                              hipStream_t stream)
{
    (void)in_sizes; (void)n_in; (void)out_size; (void)ws_size;
    const float* x     = (const float*)d_in[0];
    const float* Wq_s  = (const float*)d_in[1];
    const float* Wk_s  = (const float*)d_in[2];
    const float* Wv_s  = (const float*)d_in[3];
    const float* Wo_s  = (const float*)d_in[4];
    const float* bq_s  = (const float*)d_in[5];
    const float* bk_s  = (const float*)d_in[6];
    const float* bv_s  = (const float*)d_in[7];
    const float* bo_s  = (const float*)d_in[8];
    const float* Wq_p  = (const float*)d_in[9];
    const float* Wk_p  = (const float*)d_in[10];
    const float* Wv_p  = (const float*)d_in[11];
    const float* Wo_p  = (const float*)d_in[12];
    const float* bo_p  = (const float*)d_in[13];
    const float* Wfeat = (const float*)d_in[14];
    const float* Wg    = (const float*)d_in[15];
    const float* bg    = (const float*)d_in[16];

    float* ws = (float*)d_ws;
    const size_t NRE = (size_t)cB * cS * cE;
    float* Qs    = ws;              // later: Qp
    float* Ks    = Qs + NRE;        // later: Kp
    float* KsT   = Ks + NRE;        // later: Apout
    float* Vs    = KsT + NRE;       // later: Vp
    float* Asout = Vs + NRE;
    float* kvpart = Asout + NRE;                           // 2*32*256*64 = 1,048,576
    float* zpart  = kvpart + (size_t)2 * 32 * cM * cD;     // 2*32*256 = 16,384
    double* avgpart = (double*)(zpart + (size_t)2 * 32 * cM);  // 16*2048 doubles
    float* gates = (float*)(avgpart + (size_t)16 * 2048);  // 4

    // ---- sparse branch: BLAS-mimic fp32 q/k, fast hedged top-k ----
    gemm_qk_blas<<<dim3(16, 64), 256, 0, stream>>>(x, Wq_s, bq_s, Qs, cE, cE);
    gemm_qk_blas<<<dim3(16, 64), 256, 0, stream>>>(x, Wk_s, bk_s, Ks, cE, cE);
    gemm_f32<<<dim3(8, 32), 256, 0, stream>>>(x, Wv_s, bv_s, Vs, cE, cE);
    transpose_k<<<dim3(32, 32), 256, 0, stream>>>(Ks, KsT);
    sparse_attn<<<dim3(256, 32), 256, 0, stream>>>(Qs, KsT, Ks, Vs, Asout);

    // ---- performer branch (reuses buffers) ----
    float* Qp    = Qs;
    float* Kp    = Ks;
    float* Vp    = Vs;
    float* Apout = KsT;
    gemm_f32<<<dim3(8, 32), 256, 0, stream>>>(x, Wq_p, nullptr, Qp, cE, cE);
    gemm_f32<<<dim3(8, 32), 256, 0, stream>>>(x, Wk_p, nullptr, Kp, cE, cE);
    gemm_f32<<<dim3(8, 32), 256, 0, stream>>>(x, Wv_p, nullptr, Vp, cE, cE);
    perf_kv<<<dim3(8, 32), 256, 0, stream>>>(Kp, Vp, Wfeat, kvpart, zpart);
    perf_numden<<<dim3(32, 32), 256, 0, stream>>>(Qp, Wfeat, kvpart, zpart, Apout);

    // ---- gate + fused output ----
    gate_avg<<<dim3(8, 16), 256, 0, stream>>>(x, avgpart);
    gate_final<<<dim3(1), 128, 0, stream>>>(avgpart, Wg, bg, gates);
    out_gemm<<<dim3(16, 64), 256, 0, stream>>>(Asout, Apout, Wo_s, Wo_p,
                                               bo_s, bo_p, gates, (float*)d_out);
}

// Round 7
// 2191.413 us; speedup vs baseline: 9.3693x; 1.5502x over previous
//
#include <hip/hip_runtime.h>

// ---------------------------------------------------------------------------
// HybridThoughtAwareAttention  (B=2,S=2048,E=1024,H=16,D=64,K_TOP=64,M=256)
// Round 7: sparse_attn restructured — registers-only score/select path
// (no s16 LDS), float4 K loads, transposed Q LDS, lane-per-candidate fp64
// recompute. Selection semantics identical to rounds 4-6. Rest unchanged.
// ---------------------------------------------------------------------------

constexpr int cB = 2, cS = 2048, cE = 1024, cH = 16, cD = 64, cKTOP = 64, cM = 256;
constexpr float cEPS = 1e-6f;

__device__ __forceinline__ unsigned int f2key(float f) {    // monotone f32->u32
    unsigned int u = __float_as_uint(f);
    return (u & 0x80000000u) ? ~u : (u | 0x80000000u);
}

// ---------------------------------------------------------------------------
// OpenBLAS-sgemm-mimicking fp32 GEMM for Qs/Ks (unchanged).
// ---------------------------------------------------------------------------
__global__ __launch_bounds__(256)
void gemm_qk_blas(const float* __restrict__ A,
                  const float* __restrict__ W,
                  const float* __restrict__ bias,
                  float* __restrict__ C, int K, int N)
{
    __shared__ __align__(16) float As[16][68];
    __shared__ __align__(16) float Bs[16][68];
    const int t  = threadIdx.x;
    const int r0 = blockIdx.y * 64;
    const int c0 = blockIdx.x * 64;
    const int tm = t >> 4, tn = t & 15;
    float pacc[4][4] = {};
    float cacc[4][4] = {};

    const int ar = t >> 2, ak = (t & 3) * 4;
    const int bk = t >> 4, bc = (t & 15) * 4;

    for (int k0 = 0; k0 < K; k0 += 16) {
        const float4 av = *(const float4*)(A + (size_t)(r0 + ar) * K + (k0 + ak));
        const float4 bv = *(const float4*)(W + (size_t)(k0 + bk) * N + (c0 + bc));
        As[ak + 0][ar] = av.x;
        As[ak + 1][ar] = av.y;
        As[ak + 2][ar] = av.z;
        As[ak + 3][ar] = av.w;
        *(float4*)&Bs[bk][bc] = bv;
        __syncthreads();
        #pragma unroll
        for (int kk = 0; kk < 16; ++kk) {
            const float4 a4 = *(const float4*)&As[kk][tm * 4];
            const float4 b4 = *(const float4*)&Bs[kk][tn * 4];
            const float a[4]  = {a4.x, a4.y, a4.z, a4.w};
            const float bb[4] = {b4.x, b4.y, b4.z, b4.w};
            #pragma unroll
            for (int i = 0; i < 4; ++i)
                #pragma unroll
                for (int j = 0; j < 4; ++j)
                    pacc[i][j] = fmaf(a[i], bb[j], pacc[i][j]);
        }
        __syncthreads();
        const int kn = k0 + 16;
        if (kn == 384 || kn == 768 || kn == K) {   // OpenBLAS KC=384 panel flush
            #pragma unroll
            for (int i = 0; i < 4; ++i)
                #pragma unroll
                for (int j = 0; j < 4; ++j) {
                    cacc[i][j] = cacc[i][j] + pacc[i][j];
                    pacc[i][j] = 0.f;
                }
        }
    }
    #pragma unroll
    for (int i = 0; i < 4; ++i) {
        const int r = r0 + tm * 4 + i;
        const int c = c0 + tn * 4;
        float4 v;
        v.x = cacc[i][0] + bias[c + 0];
        v.y = cacc[i][1] + bias[c + 1];
        v.z = cacc[i][2] + bias[c + 2];
        v.w = cacc[i][3] + bias[c + 3];
        *(float4*)&C[(size_t)r * N + c] = v;
    }
}

// ---------------------------------------------------------------------------
// fp32 GEMM (smooth path): 128x128 tile, BK=8. (unchanged)
// ---------------------------------------------------------------------------
__global__ __launch_bounds__(256)
void gemm_f32(const float* __restrict__ A,
              const float* __restrict__ W,
              const float* __restrict__ bias,
              float* __restrict__ C, int K, int N)
{
    __shared__ __align__(16) float As[8][132];
    __shared__ __align__(16) float Bs[8][132];
    const int t  = threadIdx.x;
    const int r0 = blockIdx.y * 128;
    const int c0 = blockIdx.x * 128;
    const int tm = t >> 4, tn = t & 15;
    float acc[8][8] = {};

    const int ar = t >> 1;
    const int ak = (t & 1) * 4;
    const int bk = t >> 5;
    const int bc = (t & 31) * 4;

    for (int k0 = 0; k0 < K; k0 += 8) {
        const float4 av = *(const float4*)(A + (size_t)(r0 + ar) * K + (k0 + ak));
        const float4 bv = *(const float4*)(W + (size_t)(k0 + bk) * N + (c0 + bc));
        As[ak + 0][ar] = av.x;
        As[ak + 1][ar] = av.y;
        As[ak + 2][ar] = av.z;
        As[ak + 3][ar] = av.w;
        *(float4*)&Bs[bk][bc] = bv;
        __syncthreads();
        #pragma unroll
        for (int kk = 0; kk < 8; ++kk) {
            const float4 a0 = *(const float4*)&As[kk][tm * 4];
            const float4 a1 = *(const float4*)&As[kk][tm * 4 + 64];
            const float4 b0 = *(const float4*)&Bs[kk][tn * 4];
            const float4 b1 = *(const float4*)&Bs[kk][tn * 4 + 64];
            const float a[8]  = {a0.x, a0.y, a0.z, a0.w, a1.x, a1.y, a1.z, a1.w};
            const float bb[8] = {b0.x, b0.y, b0.z, b0.w, b1.x, b1.y, b1.z, b1.w};
            #pragma unroll
            for (int i = 0; i < 8; ++i)
                #pragma unroll
                for (int j = 0; j < 8; ++j)
                    acc[i][j] = fmaf(a[i], bb[j], acc[i][j]);
        }
        __syncthreads();
    }
    #pragma unroll
    for (int ih = 0; ih < 2; ++ih) {
        #pragma unroll
        for (int ii = 0; ii < 4; ++ii) {
            const int r = r0 + ih * 64 + tm * 4 + ii;
            const int i = ih * 4 + ii;
            #pragma unroll
            for (int jh = 0; jh < 2; ++jh) {
                const int c = c0 + jh * 64 + tn * 4;
                float4 v;
                v.x = acc[i][jh * 4 + 0];
                v.y = acc[i][jh * 4 + 1];
                v.z = acc[i][jh * 4 + 2];
                v.w = acc[i][jh * 4 + 3];
                if (bias) {
                    v.x += bias[c + 0]; v.y += bias[c + 1];
                    v.z += bias[c + 2]; v.w += bias[c + 3];
                }
                *(float4*)&C[(size_t)r * N + c] = v;
            }
        }
    }
}

// ---------------------------------------------------------------------------
// K transpose: (B,S,H,D) fp32 -> (B,H,D,S)  (unchanged)
// ---------------------------------------------------------------------------
__global__ __launch_bounds__(256)
void transpose_k(const float* __restrict__ Ks, float* __restrict__ KsT)
{
    __shared__ float tile[64][65];
    const int t  = threadIdx.x;
    const int bh = blockIdx.y;
    const int b  = bh >> 4;
    const int h64 = (bh & 15) * 64;
    const int s0 = blockIdx.x * 64;
    const int sr = t >> 4;
    const int d4 = (t & 15) * 4;
    #pragma unroll
    for (int i = 0; i < 4; ++i) {
        const int s = sr + 16 * i;
        float4 v = *(const float4*)&Ks[((size_t)(b * cS + s0 + s)) * cE + h64 + d4];
        tile[s][d4 + 0] = v.x; tile[s][d4 + 1] = v.y;
        tile[s][d4 + 2] = v.z; tile[s][d4 + 3] = v.w;
    }
    __syncthreads();
    const int s4 = (t & 15) * 4;
    #pragma unroll
    for (int i = 0; i < 4; ++i) {
        const int d = (t >> 4) + 16 * i;
        float4 w;
        w.x = tile[s4 + 0][d]; w.y = tile[s4 + 1][d];
        w.z = tile[s4 + 2][d]; w.w = tile[s4 + 3][d];
        *(float4*)&KsT[((size_t)(bh * 64 + d)) * cS + s0 + s4] = w;
    }
}

// ---------------------------------------------------------------------------
// Sparse attention, round-7 fast path. 8 q-rows/block, 256 threads, ~33 KB
// LDS, 4 blocks/CU. Scores + u16 select entirely in registers.
// ---------------------------------------------------------------------------
__global__ __launch_bounds__(256, 4)
void sparse_attn(const float* __restrict__ Q, const float* __restrict__ KT,
                 const float* __restrict__ Ks, const float* __restrict__ V,
                 float* __restrict__ O)
{
    __shared__ float QfT[64][8];                 // 2 KB  (Q transposed: [d][row])
    __shared__ unsigned int hist[8][257];        // 8.0 KB (pass 1, padded)
    __shared__ unsigned int hist2[8][257];       // 8.0 KB (pass 2, padded)
    __shared__ unsigned short cidx[8][128];      // 2 KB
    __shared__ double cval[8][128];              // 8 KB
    __shared__ float cw[8][128];                 // 4 KB
    __shared__ int cnt[8];
    __shared__ int t16hi[8], rem[8], t16[8];
    __shared__ double T64s[8], s65s[8], rowm[8];

    const int t   = threadIdx.x;
    const int bh  = blockIdx.y;
    const int b   = bh >> 4;
    const int h64 = (bh & 15) * 64;
    const int q0  = blockIdx.x * 8;

    if (t < 128) {
        const int r = t >> 4, c4 = (t & 15) * 4;
        const float4 v =
            *(const float4*)&Q[((size_t)(b * cS + q0 + r)) * cE + h64 + c4];
        QfT[c4 + 0][r] = v.x; QfT[c4 + 1][r] = v.y;
        QfT[c4 + 2][r] = v.z; QfT[c4 + 3][r] = v.w;
    }
    for (int i = t; i < 8 * 257; i += 256) {
        (&hist[0][0])[i]  = 0u;
        (&hist2[0][0])[i] = 0u;
    }
    if (t < 8) cnt[t] = 0;
    __syncthreads();                                               // B1

    // ---- phase A: fp32 scores, registers only. keys 4t..4t+3 (j=0) and
    //      1024+4t..+3 (j=1), 8 rows each.
    const float* KTh = KT + (size_t)bh * 64 * cS;
    float4 acc[2][8];
    #pragma unroll
    for (int j = 0; j < 2; ++j)
        #pragma unroll
        for (int r = 0; r < 8; ++r) acc[j][r] = make_float4(0.f, 0.f, 0.f, 0.f);

    #pragma unroll 4
    for (int d = 0; d < 64; ++d) {
        const float4 k0 = *(const float4*)&KTh[(size_t)d * cS + 4 * t];
        const float4 k1 = *(const float4*)&KTh[(size_t)d * cS + 1024 + 4 * t];
        const float4 qa = *(const float4*)&QfT[d][0];
        const float4 qb = *(const float4*)&QfT[d][4];
        const float qr[8] = {qa.x, qa.y, qa.z, qa.w, qb.x, qb.y, qb.z, qb.w};
        #pragma unroll
        for (int r = 0; r < 8; ++r) {
            acc[0][r].x = fmaf(qr[r], k0.x, acc[0][r].x);
            acc[0][r].y = fmaf(qr[r], k0.y, acc[0][r].y);
            acc[0][r].z = fmaf(qr[r], k0.z, acc[0][r].z);
            acc[0][r].w = fmaf(qr[r], k0.w, acc[0][r].w);
            acc[1][r].x = fmaf(qr[r], k1.x, acc[1][r].x);
            acc[1][r].y = fmaf(qr[r], k1.y, acc[1][r].y);
            acc[1][r].z = fmaf(qr[r], k1.z, acc[1][r].z);
            acc[1][r].w = fmaf(qr[r], k1.w, acc[1][r].w);
        }
    }
    // quantize to u16 keys, packed 2 per register (x|y<<16, z|w<<16)
    unsigned int su[2][8][2];
    #pragma unroll
    for (int j = 0; j < 2; ++j)
        #pragma unroll
        for (int r = 0; r < 8; ++r) {
            su[j][r][0] = (f2key(acc[j][r].x * 0.125f) >> 16)
                        | ((f2key(acc[j][r].y * 0.125f) >> 16) << 16);
            su[j][r][1] = (f2key(acc[j][r].z * 0.125f) >> 16)
                        | ((f2key(acc[j][r].w * 0.125f) >> 16) << 16);
        }

    // ---- phase B: 2-pass u16 radix select (need = 65) from registers ----
    #pragma unroll
    for (int j = 0; j < 2; ++j)
        #pragma unroll
        for (int r = 0; r < 8; ++r)
            #pragma unroll
            for (int w = 0; w < 2; ++w) {
                const unsigned int u = su[j][r][w];
                atomicAdd(&hist[r][(u & 0xFFFFu) >> 8], 1u);
                atomicAdd(&hist[r][u >> 24], 1u);
            }
    __syncthreads();                                               // B2
    if (t < 8) {
        int need = cKTOP + 1;   // 65
        int hb = 0;
        for (int bin = 255; bin >= 0; --bin) {
            const int c = (int)hist[t][bin];
            if (c >= need) { hb = bin; break; }
            need -= c;
        }
        t16hi[t] = hb;
        rem[t] = need;
    }
    __syncthreads();                                               // B3
    #pragma unroll
    for (int j = 0; j < 2; ++j)
        #pragma unroll
        for (int r = 0; r < 8; ++r) {
            const unsigned int hb = (unsigned int)t16hi[r];
            #pragma unroll
            for (int w = 0; w < 2; ++w) {
                const unsigned int u  = su[j][r][w];
                const unsigned int lo = u & 0xFFFFu;
                const unsigned int hi = u >> 16;
                if ((lo >> 8) == hb) atomicAdd(&hist2[r][lo & 255u], 1u);
                if ((hi >> 8) == hb) atomicAdd(&hist2[r][hi & 255u], 1u);
            }
        }
    __syncthreads();                                               // B4
    if (t < 8) {
        int need = rem[t];
        int lb = 0;
        for (int bin = 255; bin >= 0; --bin) {
            const int c = (int)hist2[t][bin];
            if (c >= need) { lb = bin; break; }
            need -= c;
        }
        t16[t] = (t16hi[t] << 8) | lb;
    }
    __syncthreads();                                               // B5

    // ---- candidate scan from registers: u16 >= T16 - 2 ----
    #pragma unroll
    for (int j = 0; j < 2; ++j)
        #pragma unroll
        for (int r = 0; r < 8; ++r) {
            const int thr16 = max(t16[r] - 2, 0);
            #pragma unroll
            for (int w = 0; w < 2; ++w) {
                const unsigned int u = su[j][r][w];
                const int v0 = (int)(u & 0xFFFFu);
                const int v1 = (int)(u >> 16);
                if (v0 >= thr16) {
                    const int slot = atomicAdd(&cnt[r], 1);
                    if (slot < 128)
                        cidx[r][slot] = (unsigned short)(j * 1024 + 4 * t + w * 2);
                }
                if (v1 >= thr16) {
                    const int slot = atomicAdd(&cnt[r], 1);
                    if (slot < 128)
                        cidx[r][slot] = (unsigned short)(j * 1024 + 4 * t + w * 2 + 1);
                }
            }
        }
    __syncthreads();                                               // B6

    // ---- phase C: fp64 recompute, lane = candidate (2 rows per wave) ----
    const int wv = t >> 6, lane = t & 63;
    #pragma unroll
    for (int rx = 0; rx < 2; ++rx) {
        const int rr = wv * 2 + rx;
        const int n = min(cnt[rr], 128);
        for (int c = lane; c < n; c += 64) {
            const int key = cidx[rr][c];
            const float* kp = Ks + ((size_t)(b * cS + key)) * cE + h64;
            double a = 0.0;
            #pragma unroll 4
            for (int d4 = 0; d4 < 64; d4 += 4) {
                const float4 kv = *(const float4*)&kp[d4];
                a = fma((double)QfT[d4 + 0][rr], (double)kv.x, a);
                a = fma((double)QfT[d4 + 1][rr], (double)kv.y, a);
                a = fma((double)QfT[d4 + 2][rr], (double)kv.z, a);
                a = fma((double)QfT[d4 + 3][rr], (double)kv.w, a);
            }
            cval[rr][c] = a * 0.125;
        }
    }
    __syncthreads();                                               // B7

    // ---- ranking: T64 (rank 63), s65 (rank 64), m (rank 0) ----
    #pragma unroll
    for (int rx = 0; rx < 2; ++rx) {
        const int rr = wv * 2 + rx;
        const int n = min(cnt[rr], 128);
        for (int c = lane; c < n; c += 64) {
            const double v = cval[rr][c];
            int rank = 0;
            for (int i = 0; i < n; ++i) rank += (cval[rr][i] > v) ? 1 : 0;
            if (rank == 0)  rowm[rr] = v;
            if (rank == 63) T64s[rr] = v;
            if (rank == 64) s65s[rr] = v;
        }
    }
    __syncthreads();                                               // B8

    // ---- weights: hedge formula (unchanged) ----
    #pragma unroll
    for (int rx = 0; rx < 2; ++rx) {
        const int rr = wv * 2 + rx;
        const int n = min(cnt[rr], 128);
        const double T64 = T64s[rr], s65 = s65s[rr], m = rowm[rr];
        float za = 0.f;
        for (int c = lane; c < n; c += 64) {
            const double v = cval[rr][c];
            if (v >= T64) za += expf((float)(v - m));
        }
        #pragma unroll
        for (int off = 32; off >= 1; off >>= 1)
            za += __shfl_xor(za, off);
        const float g   = (float)(T64 - s65);
        const float gm  = fmaxf(g - 5e-7f, 0.f);
        const float wB  = 0.5f * erfcf(gm * (1.0f / 2.2e-6f));
        const float wA  = 1.f - wB;
        const float e64 = expf((float)(T64 - m));
        const float e65 = expf((float)(s65 - m));
        const float ZB  = za - e64 + e65;
        const float cIn = wA / za + wB / ZB;
        const float c64 = wA / za;
        const float c65 = wB / ZB;
        for (int c = lane; c < n; c += 64) {
            const double v = cval[rr][c];
            float cc = 0.f;
            if (v > T64)       cc = cIn;
            else if (v == T64) cc = c64;
            else if (v == s65) cc = c65;
            cw[rr][c] = (cc != 0.f) ? cc * expf((float)(v - m)) : 0.f;
        }
    }
    __syncthreads();                                               // B9

    // ---- phase D: sparse PV gather (lane = output dim, 2 rows/wave) ----
    #pragma unroll
    for (int rx = 0; rx < 2; ++rx) {
        const int rr = wv * 2 + rx;
        const int n = min(cnt[rr], 128);
        float o = 0.f;
        for (int j = 0; j < n; ++j) {
            const float w = cw[rr][j];
            const int key = cidx[rr][j];
            o = fmaf(w, V[((size_t)(b * cS + key)) * cE + h64 + lane], o);
        }
        O[((size_t)(b * cS + q0 + rr)) * cE + h64 + lane] = o;
    }
}

// ---------------------------------------------------------------------------
// Performer kv (unchanged from round 6)
// ---------------------------------------------------------------------------
__global__ __launch_bounds__(256)
void perf_kv(const float* __restrict__ Kp, const float* __restrict__ Vp,
             const float* __restrict__ Wfeat,
             float* __restrict__ kvpart, float* __restrict__ zpart)
{
    __shared__ __align__(16) float Wf[64][68];
    __shared__ __align__(16) float Kt[64][68];
    __shared__ __align__(16) float Vt[64][68];
    __shared__ __align__(16) float Ph[64][68];
    const int t    = threadIdx.x;
    const int mc   = blockIdx.x & 3;
    const int sc   = blockIdx.x >> 2;          // 0 or 1
    const int bh   = blockIdx.y;
    const int b    = bh >> 4;
    const int h64  = (bh & 15) * 64;
    const int m0   = mc * 64;
    const int sbase = sc * 1024;

    #pragma unroll
    for (int i = 0; i < 4; ++i) {
        const int lin = t + 256 * i;
        const int d   = lin >> 4;
        const int m4  = (lin & 15) * 4;
        *(float4*)&Wf[d][m4] = *(const float4*)&Wfeat[d * cM + m0 + m4];
    }

    const int tm = t >> 4, tn = t & 15;
    const int sr = tm * 4;
    const int cn = tn * 4;
    float akv[4][4] = {};
    float az = 0.f;

    for (int st = 0; st < 16; ++st) {
        const int s0g = sbase + st * 64;
        __syncthreads();
        #pragma unroll
        for (int i = 0; i < 4; ++i) {
            const int row = tm + 16 * i;
            const size_t base = ((size_t)(b * cS + s0g + row)) * cE + h64 + cn;
            *(float4*)&Kt[row][cn] = *(const float4*)&Kp[base];
            *(float4*)&Vt[row][cn] = *(const float4*)&Vp[base];
        }
        __syncthreads();
        float4 p0 = {0,0,0,0}, p1 = {0,0,0,0}, p2 = {0,0,0,0}, p3 = {0,0,0,0};
        #pragma unroll 8
        for (int d = 0; d < 64; ++d) {
            const float4 wv = *(const float4*)&Wf[d][cn];
            const float k0 = Kt[sr + 0][d], k1 = Kt[sr + 1][d];
            const float k2 = Kt[sr + 2][d], k3 = Kt[sr + 3][d];
            p0.x = fmaf(k0, wv.x, p0.x); p0.y = fmaf(k0, wv.y, p0.y);
            p0.z = fmaf(k0, wv.z, p0.z); p0.w = fmaf(k0, wv.w, p0.w);
            p1.x = fmaf(k1, wv.x, p1.x); p1.y = fmaf(k1, wv.y, p1.y);
            p1.z = fmaf(k1, wv.z, p1.z); p1.w = fmaf(k1, wv.w, p1.w);
            p2.x = fmaf(k2, wv.x, p2.x); p2.y = fmaf(k2, wv.y, p2.y);
            p2.z = fmaf(k2, wv.z, p2.z); p2.w = fmaf(k2, wv.w, p2.w);
            p3.x = fmaf(k3, wv.x, p3.x); p3.y = fmaf(k3, wv.y, p3.y);
            p3.z = fmaf(k3, wv.z, p3.z); p3.w = fmaf(k3, wv.w, p3.w);
        }
        p0.x = fmaxf(p0.x, 0.f) + cEPS; p0.y = fmaxf(p0.y, 0.f) + cEPS;
        p0.z = fmaxf(p0.z, 0.f) + cEPS; p0.w = fmaxf(p0.w, 0.f) + cEPS;
        p1.x = fmaxf(p1.x, 0.f) + cEPS; p1.y = fmaxf(p1.y, 0.f) + cEPS;
        p1.z = fmaxf(p1.z, 0.f) + cEPS; p1.w = fmaxf(p1.w, 0.f) + cEPS;
        p2.x = fmaxf(p2.x, 0.f) + cEPS; p2.y = fmaxf(p2.y, 0.f) + cEPS;
        p2.z = fmaxf(p2.z, 0.f) + cEPS; p2.w = fmaxf(p2.w, 0.f) + cEPS;
        p3.x = fmaxf(p3.x, 0.f) + cEPS; p3.y = fmaxf(p3.y, 0.f) + cEPS;
        p3.z = fmaxf(p3.z, 0.f) + cEPS; p3.w = fmaxf(p3.w, 0.f) + cEPS;
        *(float4*)&Ph[sr + 0][cn] = p0;
        *(float4*)&Ph[sr + 1][cn] = p1;
        *(float4*)&Ph[sr + 2][cn] = p2;
        *(float4*)&Ph[sr + 3][cn] = p3;
        __syncthreads();
        #pragma unroll 8
        for (int ss = 0; ss < 64; ++ss) {
            const float4 pv = *(const float4*)&Ph[ss][sr];
            const float4 vv = *(const float4*)&Vt[ss][cn];
            akv[0][0] = fmaf(pv.x, vv.x, akv[0][0]); akv[0][1] = fmaf(pv.x, vv.y, akv[0][1]);
            akv[0][2] = fmaf(pv.x, vv.z, akv[0][2]); akv[0][3] = fmaf(pv.x, vv.w, akv[0][3]);
            akv[1][0] = fmaf(pv.y, vv.x, akv[1][0]); akv[1][1] = fmaf(pv.y, vv.y, akv[1][1]);
            akv[1][2] = fmaf(pv.y, vv.z, akv[1][2]); akv[1][3] = fmaf(pv.y, vv.w, akv[1][3]);
            akv[2][0] = fmaf(pv.z, vv.x, akv[2][0]); akv[2][1] = fmaf(pv.z, vv.y, akv[2][1]);
            akv[2][2] = fmaf(pv.z, vv.z, akv[2][2]); akv[2][3] = fmaf(pv.z, vv.w, akv[2][3]);
            akv[3][0] = fmaf(pv.w, vv.x, akv[3][0]); akv[3][1] = fmaf(pv.w, vv.y, akv[3][1]);
            akv[3][2] = fmaf(pv.w, vv.z, akv[3][2]); akv[3][3] = fmaf(pv.w, vv.w, akv[3][3]);
        }
        if (t < 64) {
            float a = 0.f;
            #pragma unroll 8
            for (int ss = 0; ss < 64; ++ss) a += Ph[ss][t];
            az += a;
        }
    }
    const size_t obase = ((size_t)(sc * 32 + bh)) * cM + m0;
    #pragma unroll
    for (int i = 0; i < 4; ++i) {
        float4 v; v.x = akv[i][0]; v.y = akv[i][1]; v.z = akv[i][2]; v.w = akv[i][3];
        *(float4*)&kvpart[(obase + sr + i) * cD + cn] = v;
    }
    if (t < 64) zpart[obase + t] = az;
}

// ---------------------------------------------------------------------------
// Performer num/den (unchanged from round 6)
// ---------------------------------------------------------------------------
__global__ __launch_bounds__(256)
void perf_numden(const float* __restrict__ Qp, const float* __restrict__ Wfeat,
                 const float* __restrict__ kvpart, const float* __restrict__ zpart,
                 float* __restrict__ Ap)
{
    __shared__ __align__(16) float Wf[64][68];
    __shared__ __align__(16) float Qt[64][68];
    __shared__ __align__(16) float KV[64][68];
    __shared__ __align__(16) float Ph[64][68];
    __shared__ __align__(16) float zl[64];
    __shared__ float den[64];
    const int t   = threadIdx.x;
    const int stb = blockIdx.x;
    const int bh  = blockIdx.y;
    const int b   = bh >> 4;
    const int h64 = (bh & 15) * 64;
    const int s0  = stb * 64;
    const int tm  = t >> 4, tn = t & 15;
    const int sr  = tm * 4, cn = tn * 4;

    #pragma unroll
    for (int i = 0; i < 4; ++i) {
        const int row = tm + 16 * i;
        *(float4*)&Qt[row][cn] =
            *(const float4*)&Qp[((size_t)(b * cS + s0 + row)) * cE + h64 + cn];
    }

    float num[4][4] = {};
    float dacc = 0.f;

    for (int mc = 0; mc < 4; ++mc) {
        const int m0 = mc * 64;
        __syncthreads();
        #pragma unroll
        for (int i = 0; i < 4; ++i) {
            const int lin = t + 256 * i;
            const int d   = lin >> 4;
            const int m4  = (lin & 15) * 4;
            *(float4*)&Wf[d][m4] = *(const float4*)&Wfeat[d * cM + m0 + m4];
        }
        #pragma unroll
        for (int i = 0; i < 4; ++i) {
            const int row = tm + 16 * i;
            const size_t o0 = ((size_t)bh * cM + m0 + row) * cD + cn;
            const size_t o1 = ((size_t)(32 + bh) * cM + m0 + row) * cD + cn;
            const float4 a = *(const float4*)&kvpart[o0];
            const float4 c = *(const float4*)&kvpart[o1];
            float4 v; v.x = a.x + c.x; v.y = a.y + c.y; v.z = a.z + c.z; v.w = a.w + c.w;
            *(float4*)&KV[row][cn] = v;
        }
        if (t < 64)
            zl[t] = zpart[(size_t)bh * cM + m0 + t] + zpart[(size_t)(32 + bh) * cM + m0 + t];
        __syncthreads();
        float4 p0 = {0,0,0,0}, p1 = {0,0,0,0}, p2 = {0,0,0,0}, p3 = {0,0,0,0};
        #pragma unroll 8
        for (int d = 0; d < 64; ++d) {
            const float4 wv = *(const float4*)&Wf[d][cn];
            const float q0 = Qt[sr + 0][d], q1 = Qt[sr + 1][d];
            const float q2 = Qt[sr + 2][d], q3 = Qt[sr + 3][d];
            p0.x = fmaf(q0, wv.x, p0.x); p0.y = fmaf(q0, wv.y, p0.y);
            p0.z = fmaf(q0, wv.z, p0.z); p0.w = fmaf(q0, wv.w, p0.w);
            p1.x = fmaf(q1, wv.x, p1.x); p1.y = fmaf(q1, wv.y, p1.y);
            p1.z = fmaf(q1, wv.z, p1.z); p1.w = fmaf(q1, wv.w, p1.w);
            p2.x = fmaf(q2, wv.x, p2.x); p2.y = fmaf(q2, wv.y, p2.y);
            p2.z = fmaf(q2, wv.z, p2.z); p2.w = fmaf(q2, wv.w, p2.w);
            p3.x = fmaf(q3, wv.x, p3.x); p3.y = fmaf(q3, wv.y, p3.y);
            p3.z = fmaf(q3, wv.z, p3.z); p3.w = fmaf(q3, wv.w, p3.w);
        }
        p0.x = fmaxf(p0.x, 0.f) + cEPS; p0.y = fmaxf(p0.y, 0.f) + cEPS;
        p0.z = fmaxf(p0.z, 0.f) + cEPS; p0.w = fmaxf(p0.w, 0.f) + cEPS;
        p1.x = fmaxf(p1.x, 0.f) + cEPS; p1.y = fmaxf(p1.y, 0.f) + cEPS;
        p1.z = fmaxf(p1.z, 0.f) + cEPS; p1.w = fmaxf(p1.w, 0.f) + cEPS;
        p2.x = fmaxf(p2.x, 0.f) + cEPS; p2.y = fmaxf(p2.y, 0.f) + cEPS;
        p2.z = fmaxf(p2.z, 0.f) + cEPS; p2.w = fmaxf(p2.w, 0.f) + cEPS;
        p3.x = fmaxf(p3.x, 0.f) + cEPS; p3.y = fmaxf(p3.y, 0.f) + cEPS;
        p3.z = fmaxf(p3.z, 0.f) + cEPS; p3.w = fmaxf(p3.w, 0.f) + cEPS;
        *(float4*)&Ph[sr + 0][cn] = p0;
        *(float4*)&Ph[sr + 1][cn] = p1;
        *(float4*)&Ph[sr + 2][cn] = p2;
        *(float4*)&Ph[sr + 3][cn] = p3;
        __syncthreads();
        #pragma unroll 8
        for (int mm = 0; mm < 64; ++mm) {
            const float4 kvv = *(const float4*)&KV[mm][cn];
            const float a0 = Ph[sr + 0][mm], a1 = Ph[sr + 1][mm];
            const float a2 = Ph[sr + 2][mm], a3 = Ph[sr + 3][mm];
            num[0][0] = fmaf(a0, kvv.x, num[0][0]); num[0][1] = fmaf(a0, kvv.y, num[0][1]);
            num[0][2] = fmaf(a0, kvv.z, num[0][2]); num[0][3] = fmaf(a0, kvv.w, num[0][3]);
            num[1][0] = fmaf(a1, kvv.x, num[1][0]); num[1][1] = fmaf(a1, kvv.y, num[1][1]);
            num[1][2] = fmaf(a1, kvv.z, num[1][2]); num[1][3] = fmaf(a1, kvv.w, num[1][3]);
            num[2][0] = fmaf(a2, kvv.x, num[2][0]); num[2][1] = fmaf(a2, kvv.y, num[2][1]);
            num[2][2] = fmaf(a2, kvv.z, num[2][2]); num[2][3] = fmaf(a2, kvv.w, num[2][3]);
            num[3][0] = fmaf(a3, kvv.x, num[3][0]); num[3][1] = fmaf(a3, kvv.y, num[3][1]);
            num[3][2] = fmaf(a3, kvv.z, num[3][2]); num[3][3] = fmaf(a3, kvv.w, num[3][3]);
        }
        if (t < 64) {
            float a = 0.f;
            #pragma unroll
            for (int m4 = 0; m4 < 64; m4 += 4) {
                const float4 ph = *(const float4*)&Ph[t][m4];
                const float4 zz = *(const float4*)&zl[m4];
                a = fmaf(ph.x, zz.x, a); a = fmaf(ph.y, zz.y, a);
                a = fmaf(ph.z, zz.z, a); a = fmaf(ph.w, zz.w, a);
            }
            dacc += a;
        }
    }
    __syncthreads();
    if (t < 64) den[t] = dacc + cEPS;
    __syncthreads();
    #pragma unroll
    for (int i = 0; i < 4; ++i) {
        const float di = 1.f / den[sr + i];
        float4 v;
        v.x = num[i][0] * di; v.y = num[i][1] * di;
        v.z = num[i][2] * di; v.w = num[i][3] * di;
        *(float4*)&Ap[((size_t)(b * cS + s0 + sr + i)) * cE + h64 + cn] = v;
    }
}

// ---------------------------------------------------------------------------
// Gate (unchanged from round 6)
// ---------------------------------------------------------------------------
__global__ __launch_bounds__(256)
void gate_avg(const float* __restrict__ x, double* __restrict__ avgpart)
{
    const int i  = blockIdx.x * 256 + threadIdx.x;    // 0..2047: (b,e)
    const int sc = blockIdx.y;                        // 0..15
    const int b  = i >> 10, e = i & 1023;
    double acc = 0.0;
    const int sEnd = sc * 128 + 128;
    for (int s = sc * 128; s < sEnd; ++s)
        acc += (double)x[((size_t)(b * cS + s)) * cE + e];
    avgpart[(size_t)sc * 2048 + i] = acc;
}

__global__ void gate_final(const double* __restrict__ avgpart, const float* __restrict__ Wg,
                           const float* __restrict__ bg, float* __restrict__ gates)
{
    const int t = threadIdx.x;
    const int b = t >> 6, lane = t & 63;
    float l0 = 0.f, l1 = 0.f;
    for (int e = lane; e < cE; e += 64) {
        double s = 0.0;
        #pragma unroll
        for (int sc = 0; sc < 16; ++sc)
            s += avgpart[(size_t)sc * 2048 + b * 1024 + e];
        const float a = (float)(s / (double)cS);
        l0 = fmaf(a, Wg[e * 2 + 0], l0);
        l1 = fmaf(a, Wg[e * 2 + 1], l1);
    }
    for (int off = 32; off >= 1; off >>= 1) {
        l0 += __shfl_down(l0, off);
        l1 += __shfl_down(l1, off);
    }
    if (lane == 0) {
        l0 += bg[0]; l1 += bg[1];
        const float m = fmaxf(l0, l1);
        const float e0 = expf(l0 - m), e1 = expf(l1 - m);
        const float s = e0 + e1;
        gates[b * 2 + 0] = e0 / s;
        gates[b * 2 + 1] = e1 / s;
    }
}

// ---------------------------------------------------------------------------
// Fused epilogue (unchanged)
// ---------------------------------------------------------------------------
__global__ __launch_bounds__(256)
void out_gemm(const float* __restrict__ As_, const float* __restrict__ Ap_,
              const float* __restrict__ Wos, const float* __restrict__ Wop,
              const float* __restrict__ bos, const float* __restrict__ bop,
              const float* __restrict__ gates, float* __restrict__ out)
{
    __shared__ __align__(16) float A1[16][68];
    __shared__ __align__(16) float A2[16][68];
    __shared__ __align__(16) float B1[16][68];
    __shared__ __align__(16) float B2[16][68];
    const int t  = threadIdx.x;
    const int r0 = blockIdx.y * 64, c0 = blockIdx.x * 64;
    const int tm = t >> 4, tn = t & 15;
    const int b  = r0 >> 11;
    const float gs = gates[b * 2 + 0], gp = gates[b * 2 + 1];
    float acc[4][4] = {};
    const int ar = t >> 2, ak = (t & 3) * 4;
    const int bk = t >> 4, bc = (t & 15) * 4;
    for (int k0 = 0; k0 < cE; k0 += 16) {
        const float4 a1 = *(const float4*)&As_[((size_t)(r0 + ar)) * cE + k0 + ak];
        const float4 a2 = *(const float4*)&Ap_[((size_t)(r0 + ar)) * cE + k0 + ak];
        const float4 w1 = *(const float4*)&Wos[(size_t)(k0 + bk) * cE + c0 + bc];
        const float4 w2 = *(const float4*)&Wop[(size_t)(k0 + bk) * cE + c0 + bc];
        A1[ak + 0][ar] = a1.x * gs; A1[ak + 1][ar] = a1.y * gs;
        A1[ak + 2][ar] = a1.z * gs; A1[ak + 3][ar] = a1.w * gs;
        A2[ak + 0][ar] = a2.x * gp; A2[ak + 1][ar] = a2.y * gp;
        A2[ak + 2][ar] = a2.z * gp; A2[ak + 3][ar] = a2.w * gp;
        *(float4*)&B1[bk][bc] = w1;
        *(float4*)&B2[bk][bc] = w2;
        __syncthreads();
        #pragma unroll
        for (int kk = 0; kk < 16; ++kk) {
            const float4 a1v = *(const float4*)&A1[kk][tm * 4];
            const float4 b1v = *(const float4*)&B1[kk][tn * 4];
            const float4 a2v = *(const float4*)&A2[kk][tm * 4];
            const float4 b2v = *(const float4*)&B2[kk][tn * 4];
            const float av1[4] = {a1v.x, a1v.y, a1v.z, a1v.w};
            const float bw1[4] = {b1v.x, b1v.y, b1v.z, b1v.w};
            const float av2[4] = {a2v.x, a2v.y, a2v.z, a2v.w};
            const float bw2[4] = {b2v.x, b2v.y, b2v.z, b2v.w};
            #pragma unroll
            for (int i = 0; i < 4; ++i)
                #pragma unroll
                for (int j = 0; j < 4; ++j)
                    acc[i][j] = fmaf(av2[i], bw2[j], fmaf(av1[i], bw1[j], acc[i][j]));
        }
        __syncthreads();
    }
    #pragma unroll
    for (int i = 0; i < 4; ++i) {
        const int r = r0 + tm * 4 + i;
        const int c = c0 + tn * 4;
        float4 v;
        v.x = acc[i][0] + gs * bos[c + 0] + gp * bop[c + 0];
        v.y = acc[i][1] + gs * bos[c + 1] + gp * bop[c + 1];
        v.z = acc[i][2] + gs * bos[c + 2] + gp * bop[c + 2];
        v.w = acc[i][3] + gs * bos[c + 3] + gp * bop[c + 3];
        *(float4*)&out[(size_t)r * cE + c] = v;
    }
}

// ---------------------------------------------------------------------------
extern "C" void kernel_launch(void* const* d_in, const int* in_sizes, int n_in,
                              void* d_out, int out_size, void* d_ws, size_t ws_size,
                              hipStream_t stream)
{
    (void)in_sizes; (void)n_in; (void)out_size; (void)ws_size;
    const float* x     = (const float*)d_in[0];
    const float* Wq_s  = (const float*)d_in[1];
    const float* Wk_s  = (const float*)d_in[2];
    const float* Wv_s  = (const float*)d_in[3];
    const float* Wo_s  = (const float*)d_in[4];
    const float* bq_s  = (const float*)d_in[5];
    const float* bk_s  = (const float*)d_in[6];
    const float* bv_s  = (const float*)d_in[7];
    const float* bo_s  = (const float*)d_in[8];
    const float* Wq_p  = (const float*)d_in[9];
    const float* Wk_p  = (const float*)d_in[10];
    const float* Wv_p  = (const float*)d_in[11];
    const float* Wo_p  = (const float*)d_in[12];
    const float* bo_p  = (const float*)d_in[13];
    const float* Wfeat = (const float*)d_in[14];
    const float* Wg    = (const float*)d_in[15];
    const float* bg    = (const float*)d_in[16];

    float* ws = (float*)d_ws;
    const size_t NRE = (size_t)cB * cS * cE;
    float* Qs    = ws;              // later: Qp
    float* Ks    = Qs + NRE;        // later: Kp
    float* KsT   = Ks + NRE;        // later: Apout
    float* Vs    = KsT + NRE;       // later: Vp
    float* Asout = Vs + NRE;
    float* kvpart = Asout + NRE;                           // 2*32*256*64
    float* zpart  = kvpart + (size_t)2 * 32 * cM * cD;     // 2*32*256
    double* avgpart = (double*)(zpart + (size_t)2 * 32 * cM);  // 16*2048 doubles
    float* gates = (float*)(avgpart + (size_t)16 * 2048);  // 4

    // ---- sparse branch: BLAS-mimic fp32 q/k, fast hedged top-k ----
    gemm_qk_blas<<<dim3(16, 64), 256, 0, stream>>>(x, Wq_s, bq_s, Qs, cE, cE);
    gemm_qk_blas<<<dim3(16, 64), 256, 0, stream>>>(x, Wk_s, bk_s, Ks, cE, cE);
    gemm_f32<<<dim3(8, 32), 256, 0, stream>>>(x, Wv_s, bv_s, Vs, cE, cE);
    transpose_k<<<dim3(32, 32), 256, 0, stream>>>(Ks, KsT);
    sparse_attn<<<dim3(256, 32), 256, 0, stream>>>(Qs, KsT, Ks, Vs, Asout);

    // ---- performer branch (reuses buffers) ----
    float* Qp    = Qs;
    float* Kp    = Ks;
    float* Vp    = Vs;
    float* Apout = KsT;
    gemm_f32<<<dim3(8, 32), 256, 0, stream>>>(x, Wq_p, nullptr, Qp, cE, cE);
    gemm_f32<<<dim3(8, 32), 256, 0, stream>>>(x, Wk_p, nullptr, Kp, cE, cE);
    gemm_f32<<<dim3(8, 32), 256, 0, stream>>>(x, Wv_p, nullptr, Vp, cE, cE);
    perf_kv<<<dim3(8, 32), 256, 0, stream>>>(Kp, Vp, Wfeat, kvpart, zpart);
    perf_numden<<<dim3(32, 32), 256, 0, stream>>>(Qp, Wfeat, kvpart, zpart, Apout);

    // ---- gate + fused output ----
    gate_avg<<<dim3(8, 16), 256, 0, stream>>>(x, avgpart);
    gate_final<<<dim3(1), 128, 0, stream>>>(avgpart, Wg, bg, gates);
    out_gemm<<<dim3(16, 64), 256, 0, stream>>>(Asout, Apout, Wo_s, Wo_p,
                                               bo_s, bo_p, gates, (float*)d_out);
}